// Round 8
// baseline (989.731 us; speedup 1.0000x reference)
//
#include <hip/hip_runtime.h>
#include <hip/hip_bf16.h>

// VQ argmin via MX-scaled fp8 (e4m3, scale=1.0) K=128 MFMA filter + exact
// fp64 refine. Round 8: mfma_scale_f32_16x16x128_f8f6f4 (2.25x MFMA rate),
// 64-row blocks x 4096-col halves, As 32K + slab ring-3 (80 KiB, 2 blk/CU).
// Numerics of the filter are identical to round 7 (same e4m3 products).
// Scratch carved from d_out[0:N*D) (float offsets):
//   Xq  fp8[N][512]   @ 0        (16 MiB)
//   Cq  fp8[K][512]   @ 4194304  ( 4 MiB)
//   cand int[N][192]  @ 5242880  (24 MiB)
// c2 f32[K] in d_ws.

constexpr int NTOK = 32768, DIM = 512, KCODES = 8192;
constexpr float MARGIN = 20.0f;

using ffrag = __attribute__((ext_vector_type(4))) float;   // 4 f32 acc
using i32x4 = __attribute__((ext_vector_type(4))) int;
using i32x8 = __attribute__((ext_vector_type(8))) int;

#define GLD_LDS16(g, l)                                                        \
  __builtin_amdgcn_global_load_lds(                                            \
      (const __attribute__((address_space(1))) void*)(g),                      \
      (__attribute__((address_space(3))) void*)(l), 16, 0, 0)
#define VMW(N) asm volatile("s_waitcnt vmcnt(" #N ")" ::: "memory")

// ---- f32 -> fp8 e4m3fn, explicit RNE ---------------------------------------
__device__ __forceinline__ unsigned char f2e4m3(float x) {
  unsigned u = __float_as_uint(x);
  unsigned s = (u >> 24) & 0x80u;
  float ax = fabsf(x);
  if (ax < 0.015625f) {
    int q = (int)rintf(ax * 512.0f);
    return (unsigned char)(s | (unsigned)q);
  }
  int e = (int)((u >> 23) & 0xFF) - 127;
  float m = __uint_as_float((u & 0x7FFFFFu) | 0x3F800000u);
  int r = (int)rintf(m * 8.0f);
  if (r == 16) { r = 8; ++e; }
  if (e > 8) { e = 8; r = 15; }
  return (unsigned char)(s | ((unsigned)(e + 7) << 3) | (unsigned)(r - 8));
}

// ---- convert fp32 rows -> fp8, optional sum-of-squares ---------------------
__global__ void vq_prep8(const float* __restrict__ src, unsigned char* __restrict__ dst,
                         float* __restrict__ sq, int rows) {
  int w = (blockIdx.x * blockDim.x + threadIdx.x) >> 6;
  int lane = threadIdx.x & 63;
  if (w >= rows) return;
  const float4* r4 = (const float4*)(src + (size_t)w * DIM);
  float4 a = r4[lane * 2], b = r4[lane * 2 + 1];
  union { unsigned char c[8]; uint2 v; } o;
  o.c[0]=f2e4m3(a.x); o.c[1]=f2e4m3(a.y); o.c[2]=f2e4m3(a.z); o.c[3]=f2e4m3(a.w);
  o.c[4]=f2e4m3(b.x); o.c[5]=f2e4m3(b.y); o.c[6]=f2e4m3(b.z); o.c[7]=f2e4m3(b.w);
  *(uint2*)(dst + (size_t)w * DIM + lane * 8) = o.v;
  if (sq != nullptr) {
    float s = a.x*a.x + a.y*a.y + a.z*a.z + a.w*a.w
            + b.x*b.x + b.y*b.y + b.z*b.z + b.w*b.w;
    #pragma unroll
    for (int off = 32; off; off >>= 1) s += __shfl_down(s, off, 64);
    if (lane == 0) sq[w] = s;
  }
}

// ---- fused MX-fp8 K=128 MFMA distance + best-3 + candidate emission --------
// Block: 256 thr (4 waves: wr,wc in {0,1}), 64 rows x 4096 codes (half h).
// As [64][512] pair-swizzled (32B pair-unit ^ (row&7)). Slab ring-3 of
// [128 cols][128 kB], pair-unit ^ (col&3). A-frag/B-frag: lane holds 32
// contiguous k-bytes at k-block (lane>>4)*32 (one MX scale block per lane).
__launch_bounds__(256, 2)
__global__ void vq_main(const unsigned char* __restrict__ Xq,
                        const unsigned char* __restrict__ Cq,
                        const float* __restrict__ c2g, int* __restrict__ cand) {
  __shared__ __align__(16) unsigned char As[64 * 512];     // 32 KiB
  __shared__ __align__(16) unsigned char Bs[3][16384];     // 48 KiB ring-3
  const int tid = threadIdx.x, lane = tid & 63;
  const int wid = tid >> 6, wr = wid >> 1, wc = wid & 1;
  const int rb = blockIdx.x & 511, h = blockIdx.x >> 9;
  const int row0 = rb * 64, colBase = h * 4096;
  const int l15 = lane & 15, l4 = lane >> 4;

  // ---------- prologue ----------
  float c2v[4];
  #pragma unroll
  for (int cf = 0; cf < 4; ++cf)          // c2 for ct 0
    c2v[cf] = c2g[colBase + wc * 64 + cf * 16 + l15];
  #pragma unroll
  for (int it = 0; it < 8; ++it) {        // As: pair-swizzled source
    int p = it * 256 + tid, rA = p >> 5, u = p & 31;
    GLD_LDS16(Xq + (size_t)(row0 + rA) * DIM +
                  ((((u >> 1) ^ (rA & 7)) << 5) | ((u & 1) << 4)),
              &As[0] + p * 16);
  }
  #pragma unroll
  for (int t0 = 0; t0 < 2; ++t0) {        // slabs 0,1 (kb = t0*128, ct 0)
    #pragma unroll
    for (int i = 0; i < 4; ++i) {
      int p = i * 256 + tid, c = p >> 3, u = p & 7;
      GLD_LDS16(Cq + (size_t)(colBase + c) * DIM + t0 * 128 +
                    ((((u >> 1) ^ (c & 3)) << 5) | ((u & 1) << 4)),
                &Bs[t0][0] + p * 16);
    }
  }
  VMW(4);                                  // As + slab0 landed (slab1 in flight)
  __builtin_amdgcn_s_barrier();

  i32x8 aF[2][2], bF[2][4];
  #pragma unroll
  for (int rf = 0; rf < 2; ++rf) {        // phase-0 a-frags (kp=0)
    int rA = wr * 32 + rf * 16 + l15;
    int pA = ((l4 ^ (rA & 7)) << 5);
    i32x4 lo = *(const i32x4*)(&As[0] + rA * 512 + pA);
    i32x4 hi = *(const i32x4*)(&As[0] + rA * 512 + pA + 16);
    aF[0][rf] = __builtin_shufflevector(lo, hi, 0, 1, 2, 3, 4, 5, 6, 7);
  }
  #pragma unroll
  for (int cf = 0; cf < 4; ++cf) {        // phase-0 b-frags (slab 0)
    int rB = wc * 64 + cf * 16 + l15;
    int pB = ((l4 ^ (rB & 3)) << 5);
    i32x4 lo = *(const i32x4*)(&Bs[0][0] + rB * 128 + pB);
    i32x4 hi = *(const i32x4*)(&Bs[0][0] + rB * 128 + pB + 16);
    bF[0][cf] = __builtin_shufflevector(lo, hi, 0, 1, 2, 3, 4, 5, 6, 7);
  }

  unsigned b0k[2][4], b1k[2][4], b2k[2][4];
  #pragma unroll
  for (int rf = 0; rf < 2; ++rf)
    #pragma unroll
    for (int rg = 0; rg < 4; ++rg) {
      b0k[rf][rg] = 0xFFFFFFFFu; b1k[rf][rg] = 0xFFFFFFFFu; b2k[rf][rg] = 0xFFFFFFFFu;
    }
  ffrag acc[2][4];
  int slN1 = 1, slN2 = 2;                  // ring-3 cursors: prefetch, stage

  for (int ct = 0; ct < 32; ++ct) {
    #pragma unroll
    for (int kp = 0; kp < 4; ++kp) {
      const int t = ct * 4 + kp;
      asm volatile("s_waitcnt lgkmcnt(0)" ::: "memory");
      __builtin_amdgcn_s_barrier();

      // stage slab t+2
      if (t + 2 < 128) {
        const int ts = t + 2;
        const unsigned char* csrc =
            Cq + (size_t)(colBase + (ts >> 2) * 128) * DIM + (ts & 3) * 128;
        unsigned char* ldst = &Bs[0][0] + slN2 * 16384;
        #pragma unroll
        for (int i = 0; i < 4; ++i) {
          int p = i * 256 + tid, c = p >> 3, u = p & 7;
          GLD_LDS16(csrc + (size_t)c * DIM +
                        ((((u >> 1) ^ (c & 3)) << 5) | ((u & 1) << 4)),
                    ldst + p * 16);
        }
      }
      if (kp == 0 && ct > 0) {             // c2 for this ct (used at kp==3)
        #pragma unroll
        for (int cf = 0; cf < 4; ++cf)
          c2v[cf] = c2g[colBase + ct * 128 + wc * 64 + cf * 16 + l15];
      }

      // counted vmcnt: slab t+1 (staged at t-1) proven landed
      if (t >= 126)                 { VMW(0); }
      else if (kp == 0 && ct > 0)   { VMW(8); }   // + 4 c2 loads this phase
      else                          { VMW(4); }

      // frag prefetch t+1 (lands under this phase's MFMAs)
      if (t + 1 < 128) {
        const int kpn = (kp + 1) & 3, bn = (kp + 1) & 1;
        const unsigned char* bsl = &Bs[0][0] + slN1 * 16384;
        #pragma unroll
        for (int rf = 0; rf < 2; ++rf) {
          int rA = wr * 32 + rf * 16 + l15;
          int pA = (((kpn * 4 + l4) ^ (rA & 7)) << 5);
          i32x4 lo = *(const i32x4*)(&As[0] + rA * 512 + pA);
          i32x4 hi = *(const i32x4*)(&As[0] + rA * 512 + pA + 16);
          aF[bn][rf] = __builtin_shufflevector(lo, hi, 0, 1, 2, 3, 4, 5, 6, 7);
        }
        #pragma unroll
        for (int cf = 0; cf < 4; ++cf) {
          int rB = wc * 64 + cf * 16 + l15;
          int pB = ((l4 ^ (rB & 3)) << 5);
          i32x4 lo = *(const i32x4*)(bsl + rB * 128 + pB);
          i32x4 hi = *(const i32x4*)(bsl + rB * 128 + pB + 16);
          bF[bn][cf] = __builtin_shufflevector(lo, hi, 0, 1, 2, 3, 4, 5, 6, 7);
        }
      }

      // MX MFMA, scale = 1.0 (0x7F bytes), fmt fp8-e4m3 both operands
      #pragma unroll
      for (int rf = 0; rf < 2; ++rf)
        #pragma unroll
        for (int cf = 0; cf < 4; ++cf) {
          if (kp == 0) {
            ffrag z = {0.f, 0.f, 0.f, 0.f};
            acc[rf][cf] = __builtin_amdgcn_mfma_scale_f32_16x16x128_f8f6f4(
                aF[0][rf], bF[0][cf], z, 0, 0, 0, 0x7F7F7F7F, 0, 0x7F7F7F7F);
          } else {
            acc[rf][cf] = __builtin_amdgcn_mfma_scale_f32_16x16x128_f8f6f4(
                aF[kp & 1][rf], bF[kp & 1][cf], acc[rf][cf],
                0, 0, 0, 0x7F7F7F7F, 0, 0x7F7F7F7F);
          }
        }

      if (kp == 3) {   // per-ct epilogue: insert all 4 cf keys into best-3
        #pragma unroll
        for (int rf = 0; rf < 2; ++rf)
          #pragma unroll
          for (int rg = 0; rg < 4; ++rg) {
            #pragma unroll
            for (int cf = 0; cf < 4; ++cf) {
              float d = fmaf(-2.0f, acc[rf][cf][rg], c2v[cf] + 2048.0f);
              unsigned k = (__float_as_uint(d) & 0xFFFFFF00u) |
                           (unsigned)((ct << 2) | cf);
              unsigned lo0 = min(b0k[rf][rg], k), hi0 = max(b0k[rf][rg], k);
              b0k[rf][rg] = lo0;
              unsigned lo1 = min(b1k[rf][rg], hi0), hi1 = max(b1k[rf][rg], hi0);
              b1k[rf][rg] = lo1;
              b2k[rf][rg] = min(b2k[rf][rg], hi1);
            }
          }
      }
      // rotate ring cursors
      slN1 = slN2;
      slN2 = (slN2 == 2) ? 0 : slN2 + 1;
    }  // kp
  }    // ct

  asm volatile("s_waitcnt lgkmcnt(0)" ::: "memory");
  VMW(0);
  __builtin_amdgcn_s_barrier();

  // per-row min across 16 l15-lanes; cross-wc merge via LDS (overlay on Bs)
  unsigned* dstar = (unsigned*)&Bs[0][0];   // [2][64]
  unsigned gmin[2][4];
  #pragma unroll
  for (int rf = 0; rf < 2; ++rf)
    #pragma unroll
    for (int rg = 0; rg < 4; ++rg) {
      unsigned g = b0k[rf][rg];
      #pragma unroll
      for (int m = 1; m < 16; m <<= 1)
        g = min(g, (unsigned)__shfl_xor((int)g, m, 64));
      gmin[rf][rg] = g;
      if (l15 == 0) dstar[wc * 64 + wr * 32 + rf * 16 + l4 * 4 + rg] = g;
    }
  __syncthreads();
  #pragma unroll
  for (int rf = 0; rf < 2; ++rf)
    #pragma unroll
    for (int rg = 0; rg < 4; ++rg) {
      int rl = wr * 32 + rf * 16 + l4 * 4 + rg;
      unsigned gg = min(gmin[rf][rg], dstar[(wc ^ 1) * 64 + rl]);
      float ds = __uint_as_float(gg & 0xFFFFFF00u);
      unsigned thr = __float_as_uint(ds + MARGIN);
      int base = (row0 + rl) * 192 + h * 96 + wc * 48 + l15 * 3;
      unsigned kk0 = b0k[rf][rg], kk1 = b1k[rf][rg], kk2 = b2k[rf][rg];
      int c0 = colBase + (int)((kk0 >> 2) & 31u) * 128 + wc * 64 + (int)(kk0 & 3u) * 16 + l15;
      int c1 = colBase + (int)((kk1 >> 2) & 31u) * 128 + wc * 64 + (int)(kk1 & 3u) * 16 + l15;
      int c2i = colBase + (int)((kk2 >> 2) & 31u) * 128 + wc * 64 + (int)(kk2 & 3u) * 16 + l15;
      cand[base + 0] = (kk0 <= thr) ? c0 : -1;
      cand[base + 1] = (kk1 <= thr) ? c1 : -1;
      cand[base + 2] = (kk2 <= thr) ? c2i : -1;
    }
}

// ---- exact fp64 refine over candidate set (one wave per row, 192 slots) ----
__global__ void vq_refine(const float* __restrict__ X, const float* __restrict__ Cb,
                          const int* __restrict__ cand, float* __restrict__ idx_out) {
  int row = (blockIdx.x * blockDim.x + threadIdx.x) >> 6;
  int lane = threadIdx.x & 63;
  if (row >= NTOK) return;
  int cv0 = cand[row * 192 + lane];
  int cv1 = cand[row * 192 + 64 + lane];
  int cv2 = cand[row * 192 + 128 + lane];
  unsigned long long m0 = __ballot(cv0 >= 0);
  unsigned long long m1 = __ballot(cv1 >= 0);
  unsigned long long m2 = __ballot(cv2 >= 0);
  if (__popcll(m0) + __popcll(m1) + __popcll(m2) == 1) {
    int idx;
    if (m0)      idx = __shfl(cv0, __ffsll(m0) - 1, 64);
    else if (m1) idx = __shfl(cv1, __ffsll(m1) - 1, 64);
    else         idx = __shfl(cv2, __ffsll(m2) - 1, 64);
    if (lane == 0) idx_out[row] = (float)idx;
    return;
  }
  const float4* x4 = (const float4*)(X + (size_t)row * DIM);
  float4 xa = x4[lane * 2], xb = x4[lane * 2 + 1];
  double bestd = 1e300; int besti = 0x7FFFFFFF;
  #pragma unroll
  for (int part = 0; part < 3; ++part) {
    unsigned long long mm = part == 0 ? m0 : (part == 1 ? m1 : m2);
    int cv = part == 0 ? cv0 : (part == 1 ? cv1 : cv2);
    while (mm) {
      int src = __ffsll(mm) - 1; mm &= mm - 1;
      int idx = __shfl(cv, src, 64);
      const float4* c4 = (const float4*)(Cb + (size_t)idx * DIM);
      float4 ca = c4[lane * 2], cb = c4[lane * 2 + 1];
      double dt = (double)xa.x*ca.x + (double)xa.y*ca.y + (double)xa.z*ca.z + (double)xa.w*ca.w
                + (double)xb.x*cb.x + (double)xb.y*cb.y + (double)xb.z*cb.z + (double)xb.w*cb.w;
      double cc = (double)ca.x*ca.x + (double)ca.y*ca.y + (double)ca.z*ca.z + (double)ca.w*ca.w
                + (double)cb.x*cb.x + (double)cb.y*cb.y + (double)cb.z*cb.z + (double)cb.w*cb.w;
      double sdist = cc - 2.0 * dt;           // x2 omitted: per-row constant
      #pragma unroll
      for (int off = 32; off; off >>= 1) sdist += __shfl_down(sdist, off, 64);
      if (lane == 0 && (sdist < bestd || (sdist == bestd && idx < besti))) { bestd = sdist; besti = idx; }
    }
  }
  if (lane == 0) idx_out[row] = (float)besti;
}

// ---- final: quantized = inputs (runs LAST; overwrites scratch) -------------
__global__ void vq_copy(const float* __restrict__ in, float* __restrict__ out, int n4) {
  int i = blockIdx.x * blockDim.x + threadIdx.x;
  int st = gridDim.x * blockDim.x;
  const float4* s = (const float4*)in;
  float4* d = (float4*)out;
  for (; i < n4; i += st) d[i] = s[i];
}

extern "C" void kernel_launch(void* const* d_in, const int* in_sizes, int n_in,
                              void* d_out, int out_size, void* d_ws, size_t ws_size,
                              hipStream_t stream) {
  const float* X  = (const float*)d_in[0];
  const float* Cb = (const float*)d_in[1];
  float* out = (float*)d_out;

  unsigned char* Xq   = (unsigned char*)out;                  // [N][512] fp8
  unsigned char* Cq   = (unsigned char*)(out + 4194304);      // [K][512] fp8
  int*           cand = (int*)(out + 5242880);                // [N][192]
  float*         c2   = (float*)d_ws;                         // [K]
  float*         idx_out = out + (size_t)NTOK * DIM;

  vq_prep8<<<KCODES / 4, 256, 0, stream>>>(Cb, Cq, c2, KCODES);
  vq_prep8<<<NTOK / 4, 256, 0, stream>>>(X, Xq, nullptr, NTOK);
  vq_main<<<1024, 256, 0, stream>>>(Xq, Cq, c2, cand);
  vq_refine<<<NTOK / 4, 256, 0, stream>>>(X, Cb, cand, idx_out);
  vq_copy<<<2048, 256, 0, stream>>>(X, out, NTOK * DIM / 4);
}

// Round 9
// 773.016 us; speedup vs baseline: 1.2804x; 1.2804x over previous
//
#include <hip/hip_runtime.h>
#include <hip/hip_bf16.h>

// VQ argmin via MX-scaled fp8 (e4m3, scale=1.0) K=128 MFMA filter + exact
// fp64 refine. Round 9: fix round-8's L2 thrash — grid = 512 = exact
// co-residency capacity (2 blocks/CU), each block walks the FULL codebook
// (64 ct x 4 kp = 256 phases), so all blocks stay phase-locked and Cq (4 MB)
// is served once from L2 per XCD. Addressing/swizzles/VMW identical to r8.
// Scratch carved from d_out[0:N*D) (float offsets):
//   Xq  fp8[N][512]   @ 0        (16 MiB)
//   Cq  fp8[K][512]   @ 4194304  ( 4 MiB)
//   cand int[N][96]   @ 5242880  (12 MiB)
// c2 f32[K] in d_ws.

constexpr int NTOK = 32768, DIM = 512, KCODES = 8192;
constexpr float MARGIN = 20.0f;

using ffrag = __attribute__((ext_vector_type(4))) float;   // 4 f32 acc
using i32x4 = __attribute__((ext_vector_type(4))) int;
using i32x8 = __attribute__((ext_vector_type(8))) int;

#define GLD_LDS16(g, l)                                                        \
  __builtin_amdgcn_global_load_lds(                                            \
      (const __attribute__((address_space(1))) void*)(g),                      \
      (__attribute__((address_space(3))) void*)(l), 16, 0, 0)
#define VMW(N) asm volatile("s_waitcnt vmcnt(" #N ")" ::: "memory")

// ---- f32 -> fp8 e4m3fn, explicit RNE ---------------------------------------
__device__ __forceinline__ unsigned char f2e4m3(float x) {
  unsigned u = __float_as_uint(x);
  unsigned s = (u >> 24) & 0x80u;
  float ax = fabsf(x);
  if (ax < 0.015625f) {
    int q = (int)rintf(ax * 512.0f);
    return (unsigned char)(s | (unsigned)q);
  }
  int e = (int)((u >> 23) & 0xFF) - 127;
  float m = __uint_as_float((u & 0x7FFFFFu) | 0x3F800000u);
  int r = (int)rintf(m * 8.0f);
  if (r == 16) { r = 8; ++e; }
  if (e > 8) { e = 8; r = 15; }
  return (unsigned char)(s | ((unsigned)(e + 7) << 3) | (unsigned)(r - 8));
}

// ---- convert fp32 rows -> fp8, optional sum-of-squares ---------------------
__global__ void vq_prep8(const float* __restrict__ src, unsigned char* __restrict__ dst,
                         float* __restrict__ sq, int rows) {
  int w = (blockIdx.x * blockDim.x + threadIdx.x) >> 6;
  int lane = threadIdx.x & 63;
  if (w >= rows) return;
  const float4* r4 = (const float4*)(src + (size_t)w * DIM);
  float4 a = r4[lane * 2], b = r4[lane * 2 + 1];
  union { unsigned char c[8]; uint2 v; } o;
  o.c[0]=f2e4m3(a.x); o.c[1]=f2e4m3(a.y); o.c[2]=f2e4m3(a.z); o.c[3]=f2e4m3(a.w);
  o.c[4]=f2e4m3(b.x); o.c[5]=f2e4m3(b.y); o.c[6]=f2e4m3(b.z); o.c[7]=f2e4m3(b.w);
  *(uint2*)(dst + (size_t)w * DIM + lane * 8) = o.v;
  if (sq != nullptr) {
    float s = a.x*a.x + a.y*a.y + a.z*a.z + a.w*a.w
            + b.x*b.x + b.y*b.y + b.z*b.z + b.w*b.w;
    #pragma unroll
    for (int off = 32; off; off >>= 1) s += __shfl_down(s, off, 64);
    if (lane == 0) sq[w] = s;
  }
}

// ---- fused MX-fp8 K=128 MFMA distance + best-3 + candidate emission --------
// Block: 256 thr (4 waves: wr,wc in {0,1}), 64 rows x FULL 8192 codes.
// As [64][512] pair-swizzled (32B pair-unit ^ (row&7)). Slab ring-3 of
// [128 cols][128 kB], pair-unit ^ (col&3). Lane holds 32 contiguous k-bytes
// at k-block (lane>>4)*32 (one MX scale block per lane; scale bytes = 0x7F).
__launch_bounds__(256, 2)
__global__ void vq_main(const unsigned char* __restrict__ Xq,
                        const unsigned char* __restrict__ Cq,
                        const float* __restrict__ c2g, int* __restrict__ cand) {
  __shared__ __align__(16) unsigned char As[64 * 512];     // 32 KiB
  __shared__ __align__(16) unsigned char Bs[3][16384];     // 48 KiB ring-3
  const int tid = threadIdx.x, lane = tid & 63;
  const int wid = tid >> 6, wr = wid >> 1, wc = wid & 1;
  const int row0 = blockIdx.x * 64;
  const int l15 = lane & 15, l4 = lane >> 4;
  constexpr int TT = 64 * 4;   // 256 phases (64 ct x 4 k-slabs)

  // ---------- prologue ----------
  float c2v[4];
  #pragma unroll
  for (int cf = 0; cf < 4; ++cf)          // c2 for ct 0
    c2v[cf] = c2g[wc * 64 + cf * 16 + l15];
  #pragma unroll
  for (int it = 0; it < 8; ++it) {        // As: pair-swizzled source
    int p = it * 256 + tid, rA = p >> 5, u = p & 31;
    GLD_LDS16(Xq + (size_t)(row0 + rA) * DIM +
                  ((((u >> 1) ^ (rA & 7)) << 5) | ((u & 1) << 4)),
              &As[0] + p * 16);
  }
  #pragma unroll
  for (int t0 = 0; t0 < 2; ++t0) {        // slabs 0,1 (ct 0, kb = t0*128)
    #pragma unroll
    for (int i = 0; i < 4; ++i) {
      int p = i * 256 + tid, c = p >> 3, u = p & 7;
      GLD_LDS16(Cq + (size_t)c * DIM + t0 * 128 +
                    ((((u >> 1) ^ (c & 3)) << 5) | ((u & 1) << 4)),
                &Bs[t0][0] + p * 16);
    }
  }
  VMW(4);                                  // c2+As+slab0 landed (slab1 flying)
  __builtin_amdgcn_s_barrier();

  i32x8 aF[2][2], bF[2][4];
  #pragma unroll
  for (int rf = 0; rf < 2; ++rf) {        // phase-0 a-frags (kp=0)
    int rA = wr * 32 + rf * 16 + l15;
    int pA = ((l4 ^ (rA & 7)) << 5);
    i32x4 lo = *(const i32x4*)(&As[0] + rA * 512 + pA);
    i32x4 hi = *(const i32x4*)(&As[0] + rA * 512 + pA + 16);
    aF[0][rf] = __builtin_shufflevector(lo, hi, 0, 1, 2, 3, 4, 5, 6, 7);
  }
  #pragma unroll
  for (int cf = 0; cf < 4; ++cf) {        // phase-0 b-frags (slab 0)
    int rB = wc * 64 + cf * 16 + l15;
    int pB = ((l4 ^ (rB & 3)) << 5);
    i32x4 lo = *(const i32x4*)(&Bs[0][0] + rB * 128 + pB);
    i32x4 hi = *(const i32x4*)(&Bs[0][0] + rB * 128 + pB + 16);
    bF[0][cf] = __builtin_shufflevector(lo, hi, 0, 1, 2, 3, 4, 5, 6, 7);
  }

  unsigned b0k[2][4], b1k[2][4], b2k[2][4];
  #pragma unroll
  for (int rf = 0; rf < 2; ++rf)
    #pragma unroll
    for (int rg = 0; rg < 4; ++rg) {
      b0k[rf][rg] = 0xFFFFFFFFu; b1k[rf][rg] = 0xFFFFFFFFu; b2k[rf][rg] = 0xFFFFFFFFu;
    }
  ffrag acc[2][4];
  int slN1 = 1, slN2 = 2;                  // ring-3 cursors: prefetch, stage

  for (int ct = 0; ct < 64; ++ct) {
    #pragma unroll
    for (int kp = 0; kp < 4; ++kp) {
      const int t = ct * 4 + kp;
      asm volatile("s_waitcnt lgkmcnt(0)" ::: "memory");
      __builtin_amdgcn_s_barrier();

      // stage slab t+2
      if (t + 2 < TT) {
        const int ts = t + 2;
        const unsigned char* csrc =
            Cq + (size_t)((ts >> 2) * 128) * DIM + (ts & 3) * 128;
        unsigned char* ldst = &Bs[0][0] + slN2 * 16384;
        #pragma unroll
        for (int i = 0; i < 4; ++i) {
          int p = i * 256 + tid, c = p >> 3, u = p & 7;
          GLD_LDS16(csrc + (size_t)c * DIM +
                        ((((u >> 1) ^ (c & 3)) << 5) | ((u & 1) << 4)),
                    ldst + p * 16);
        }
      }
      if (kp == 0 && ct > 0) {             // c2 for this ct (used at kp==3)
        #pragma unroll
        for (int cf = 0; cf < 4; ++cf)
          c2v[cf] = c2g[ct * 128 + wc * 64 + cf * 16 + l15];
      }

      // counted vmcnt: slab t+1 (staged at t-1) proven landed
      if (t >= TT - 2)              { VMW(0); }
      else if (kp == 0 && ct > 0)   { VMW(8); }   // + 4 c2 loads this phase
      else                          { VMW(4); }

      // frag prefetch t+1 (lands under this phase's MFMAs)
      if (t + 1 < TT) {
        const int kpn = (kp + 1) & 3, bn = (kp + 1) & 1;
        const unsigned char* bsl = &Bs[0][0] + slN1 * 16384;
        #pragma unroll
        for (int rf = 0; rf < 2; ++rf) {
          int rA = wr * 32 + rf * 16 + l15;
          int pA = (((kpn * 4 + l4) ^ (rA & 7)) << 5);
          i32x4 lo = *(const i32x4*)(&As[0] + rA * 512 + pA);
          i32x4 hi = *(const i32x4*)(&As[0] + rA * 512 + pA + 16);
          aF[bn][rf] = __builtin_shufflevector(lo, hi, 0, 1, 2, 3, 4, 5, 6, 7);
        }
        #pragma unroll
        for (int cf = 0; cf < 4; ++cf) {
          int rB = wc * 64 + cf * 16 + l15;
          int pB = ((l4 ^ (rB & 3)) << 5);
          i32x4 lo = *(const i32x4*)(bsl + rB * 128 + pB);
          i32x4 hi = *(const i32x4*)(bsl + rB * 128 + pB + 16);
          bF[bn][cf] = __builtin_shufflevector(lo, hi, 0, 1, 2, 3, 4, 5, 6, 7);
        }
      }

      // MX MFMA, scale = 1.0 (0x7F bytes), fmt fp8-e4m3 both operands
      #pragma unroll
      for (int rf = 0; rf < 2; ++rf)
        #pragma unroll
        for (int cf = 0; cf < 4; ++cf) {
          if (kp == 0) {
            ffrag z = {0.f, 0.f, 0.f, 0.f};
            acc[rf][cf] = __builtin_amdgcn_mfma_scale_f32_16x16x128_f8f6f4(
                aF[0][rf], bF[0][cf], z, 0, 0, 0, 0x7F7F7F7F, 0, 0x7F7F7F7F);
          } else {
            acc[rf][cf] = __builtin_amdgcn_mfma_scale_f32_16x16x128_f8f6f4(
                aF[kp & 1][rf], bF[kp & 1][cf], acc[rf][cf],
                0, 0, 0, 0x7F7F7F7F, 0, 0x7F7F7F7F);
          }
        }

      if (kp == 3) {   // per-ct epilogue: insert all 4 cf keys into best-3
        #pragma unroll
        for (int rf = 0; rf < 2; ++rf)
          #pragma unroll
          for (int rg = 0; rg < 4; ++rg) {
            #pragma unroll
            for (int cf = 0; cf < 4; ++cf) {
              float d = fmaf(-2.0f, acc[rf][cf][rg], c2v[cf] + 2048.0f);
              unsigned k = (__float_as_uint(d) & 0xFFFFFF00u) |
                           (unsigned)((ct << 2) | cf);   // ct<64 -> 8 bits
              unsigned lo0 = min(b0k[rf][rg], k), hi0 = max(b0k[rf][rg], k);
              b0k[rf][rg] = lo0;
              unsigned lo1 = min(b1k[rf][rg], hi0), hi1 = max(b1k[rf][rg], hi0);
              b1k[rf][rg] = lo1;
              b2k[rf][rg] = min(b2k[rf][rg], hi1);
            }
          }
      }
      // rotate ring cursors
      slN1 = slN2;
      slN2 = (slN2 == 2) ? 0 : slN2 + 1;
    }  // kp
  }    // ct

  asm volatile("s_waitcnt lgkmcnt(0)" ::: "memory");
  VMW(0);
  __builtin_amdgcn_s_barrier();

  // per-row min across 16 l15-lanes; cross-wc merge via LDS (overlay on Bs)
  unsigned* dstar = (unsigned*)&Bs[0][0];   // [2][64]
  unsigned gmin[2][4];
  #pragma unroll
  for (int rf = 0; rf < 2; ++rf)
    #pragma unroll
    for (int rg = 0; rg < 4; ++rg) {
      unsigned g = b0k[rf][rg];
      #pragma unroll
      for (int m = 1; m < 16; m <<= 1)
        g = min(g, (unsigned)__shfl_xor((int)g, m, 64));
      gmin[rf][rg] = g;
      if (l15 == 0) dstar[wc * 64 + wr * 32 + rf * 16 + l4 * 4 + rg] = g;
    }
  __syncthreads();
  #pragma unroll
  for (int rf = 0; rf < 2; ++rf)
    #pragma unroll
    for (int rg = 0; rg < 4; ++rg) {
      int rl = wr * 32 + rf * 16 + l4 * 4 + rg;
      unsigned gg = min(gmin[rf][rg], dstar[(wc ^ 1) * 64 + rl]);
      float ds = __uint_as_float(gg & 0xFFFFFF00u);
      unsigned thr = __float_as_uint(ds + MARGIN);
      int base = (row0 + rl) * 96 + wc * 48 + l15 * 3;
      unsigned kk0 = b0k[rf][rg], kk1 = b1k[rf][rg], kk2 = b2k[rf][rg];
      int c0 = (int)((kk0 >> 2) & 63u) * 128 + wc * 64 + (int)(kk0 & 3u) * 16 + l15;
      int c1 = (int)((kk1 >> 2) & 63u) * 128 + wc * 64 + (int)(kk1 & 3u) * 16 + l15;
      int c2i = (int)((kk2 >> 2) & 63u) * 128 + wc * 64 + (int)(kk2 & 3u) * 16 + l15;
      cand[base + 0] = (kk0 <= thr) ? c0 : -1;
      cand[base + 1] = (kk1 <= thr) ? c1 : -1;
      cand[base + 2] = (kk2 <= thr) ? c2i : -1;
    }
}

// ---- exact fp64 refine over candidate set (one wave per row, 96 slots) -----
__global__ void vq_refine(const float* __restrict__ X, const float* __restrict__ Cb,
                          const int* __restrict__ cand, float* __restrict__ idx_out) {
  int row = (blockIdx.x * blockDim.x + threadIdx.x) >> 6;
  int lane = threadIdx.x & 63;
  if (row >= NTOK) return;
  int cv0 = cand[row * 96 + lane];
  int cv1 = (lane < 32) ? cand[row * 96 + 64 + lane] : -1;
  unsigned long long m0 = __ballot(cv0 >= 0);
  unsigned long long m1 = __ballot(cv1 >= 0);
  if (__popcll(m0) + __popcll(m1) == 1) {
    int idx;
    if (m0) idx = __shfl(cv0, __ffsll(m0) - 1, 64);
    else    idx = __shfl(cv1, __ffsll(m1) - 1, 64);
    if (lane == 0) idx_out[row] = (float)idx;
    return;
  }
  const float4* x4 = (const float4*)(X + (size_t)row * DIM);
  float4 xa = x4[lane * 2], xb = x4[lane * 2 + 1];
  double bestd = 1e300; int besti = 0x7FFFFFFF;
  #pragma unroll
  for (int part = 0; part < 2; ++part) {
    unsigned long long mm = part == 0 ? m0 : m1;
    int cv = part == 0 ? cv0 : cv1;
    while (mm) {
      int src = __ffsll(mm) - 1; mm &= mm - 1;
      int idx = __shfl(cv, src, 64);
      const float4* c4 = (const float4*)(Cb + (size_t)idx * DIM);
      float4 ca = c4[lane * 2], cb = c4[lane * 2 + 1];
      double dt = (double)xa.x*ca.x + (double)xa.y*ca.y + (double)xa.z*ca.z + (double)xa.w*ca.w
                + (double)xb.x*cb.x + (double)xb.y*cb.y + (double)xb.z*cb.z + (double)xb.w*cb.w;
      double cc = (double)ca.x*ca.x + (double)ca.y*ca.y + (double)ca.z*ca.z + (double)ca.w*ca.w
                + (double)cb.x*cb.x + (double)cb.y*cb.y + (double)cb.z*cb.z + (double)cb.w*cb.w;
      double sdist = cc - 2.0 * dt;           // x2 omitted: per-row constant
      #pragma unroll
      for (int off = 32; off; off >>= 1) sdist += __shfl_down(sdist, off, 64);
      if (lane == 0 && (sdist < bestd || (sdist == bestd && idx < besti))) { bestd = sdist; besti = idx; }
    }
  }
  if (lane == 0) idx_out[row] = (float)besti;
}

// ---- final: quantized = inputs (runs LAST; overwrites scratch) -------------
__global__ void vq_copy(const float* __restrict__ in, float* __restrict__ out, int n4) {
  int i = blockIdx.x * blockDim.x + threadIdx.x;
  int st = gridDim.x * blockDim.x;
  const float4* s = (const float4*)in;
  float4* d = (float4*)out;
  for (; i < n4; i += st) d[i] = s[i];
}

extern "C" void kernel_launch(void* const* d_in, const int* in_sizes, int n_in,
                              void* d_out, int out_size, void* d_ws, size_t ws_size,
                              hipStream_t stream) {
  const float* X  = (const float*)d_in[0];
  const float* Cb = (const float*)d_in[1];
  float* out = (float*)d_out;

  unsigned char* Xq   = (unsigned char*)out;                  // [N][512] fp8
  unsigned char* Cq   = (unsigned char*)(out + 4194304);      // [K][512] fp8
  int*           cand = (int*)(out + 5242880);                // [N][96]
  float*         c2   = (float*)d_ws;                         // [K]
  float*         idx_out = out + (size_t)NTOK * DIM;

  vq_prep8<<<KCODES / 4, 256, 0, stream>>>(Cb, Cq, c2, KCODES);
  vq_prep8<<<NTOK / 4, 256, 0, stream>>>(X, Xq, nullptr, NTOK);
  vq_main<<<NTOK / 64, 256, 0, stream>>>(Xq, Cq, c2, cand);
  vq_refine<<<NTOK / 4, 256, 0, stream>>>(X, Cb, cand, idx_out);
  vq_copy<<<2048, 256, 0, stream>>>(X, out, NTOK * DIM / 4);
}

// Round 10
// 772.185 us; speedup vs baseline: 1.2817x; 1.0011x over previous
//
#include <hip/hip_runtime.h>
#include <hip/hip_bf16.h>

// VQ argmin via MX-scaled fp8 (e4m3, scale=1.0) K=128 MFMA filter + exact
// fp64 refine. Round 10: fix round-9's register SPILL (WRITE_SIZE 1.6GB,
// VGPR=128): __launch_bounds__(256,2) only sets a MIN waves/EU, so LLVM
// aimed for 4 waves/EU (128-VGPR cap) and spilled the i32x8 fragment
// buffers to scratch every phase. Pin amdgpu_waves_per_eu(2,2) -> 256-VGPR
// budget, no spill. Kernel body byte-identical to round 9.
// Scratch carved from d_out[0:N*D) (float offsets):
//   Xq  fp8[N][512]   @ 0        (16 MiB)
//   Cq  fp8[K][512]   @ 4194304  ( 4 MiB)
//   cand int[N][96]   @ 5242880  (12 MiB)
// c2 f32[K] in d_ws.

constexpr int NTOK = 32768, DIM = 512, KCODES = 8192;
constexpr float MARGIN = 20.0f;

using ffrag = __attribute__((ext_vector_type(4))) float;   // 4 f32 acc
using i32x4 = __attribute__((ext_vector_type(4))) int;
using i32x8 = __attribute__((ext_vector_type(8))) int;

#define GLD_LDS16(g, l)                                                        \
  __builtin_amdgcn_global_load_lds(                                            \
      (const __attribute__((address_space(1))) void*)(g),                      \
      (__attribute__((address_space(3))) void*)(l), 16, 0, 0)
#define VMW(N) asm volatile("s_waitcnt vmcnt(" #N ")" ::: "memory")

// ---- f32 -> fp8 e4m3fn, explicit RNE ---------------------------------------
__device__ __forceinline__ unsigned char f2e4m3(float x) {
  unsigned u = __float_as_uint(x);
  unsigned s = (u >> 24) & 0x80u;
  float ax = fabsf(x);
  if (ax < 0.015625f) {
    int q = (int)rintf(ax * 512.0f);
    return (unsigned char)(s | (unsigned)q);
  }
  int e = (int)((u >> 23) & 0xFF) - 127;
  float m = __uint_as_float((u & 0x7FFFFFu) | 0x3F800000u);
  int r = (int)rintf(m * 8.0f);
  if (r == 16) { r = 8; ++e; }
  if (e > 8) { e = 8; r = 15; }
  return (unsigned char)(s | ((unsigned)(e + 7) << 3) | (unsigned)(r - 8));
}

// ---- convert fp32 rows -> fp8, optional sum-of-squares ---------------------
__global__ void vq_prep8(const float* __restrict__ src, unsigned char* __restrict__ dst,
                         float* __restrict__ sq, int rows) {
  int w = (blockIdx.x * blockDim.x + threadIdx.x) >> 6;
  int lane = threadIdx.x & 63;
  if (w >= rows) return;
  const float4* r4 = (const float4*)(src + (size_t)w * DIM);
  float4 a = r4[lane * 2], b = r4[lane * 2 + 1];
  union { unsigned char c[8]; uint2 v; } o;
  o.c[0]=f2e4m3(a.x); o.c[1]=f2e4m3(a.y); o.c[2]=f2e4m3(a.z); o.c[3]=f2e4m3(a.w);
  o.c[4]=f2e4m3(b.x); o.c[5]=f2e4m3(b.y); o.c[6]=f2e4m3(b.z); o.c[7]=f2e4m3(b.w);
  *(uint2*)(dst + (size_t)w * DIM + lane * 8) = o.v;
  if (sq != nullptr) {
    float s = a.x*a.x + a.y*a.y + a.z*a.z + a.w*a.w
            + b.x*b.x + b.y*b.y + b.z*b.z + b.w*b.w;
    #pragma unroll
    for (int off = 32; off; off >>= 1) s += __shfl_down(s, off, 64);
    if (lane == 0) sq[w] = s;
  }
}

// ---- fused MX-fp8 K=128 MFMA distance + best-3 + candidate emission --------
// Block: 256 thr (4 waves: wr,wc in {0,1}), 64 rows x FULL 8192 codes.
// As [64][512] pair-swizzled (32B pair-unit ^ (row&7)). Slab ring-3 of
// [128 cols][128 kB], pair-unit ^ (col&3). Lane holds 32 contiguous k-bytes
// at k-block (lane>>4)*32 (one MX scale block per lane; scale bytes = 0x7F).
__attribute__((amdgpu_waves_per_eu(2, 2)))   // pin: 2 waves/EU -> 256-VGPR cap
__launch_bounds__(256)
__global__ void vq_main(const unsigned char* __restrict__ Xq,
                        const unsigned char* __restrict__ Cq,
                        const float* __restrict__ c2g, int* __restrict__ cand) {
  __shared__ __align__(16) unsigned char As[64 * 512];     // 32 KiB
  __shared__ __align__(16) unsigned char Bs[3][16384];     // 48 KiB ring-3
  const int tid = threadIdx.x, lane = tid & 63;
  const int wid = tid >> 6, wr = wid >> 1, wc = wid & 1;
  const int row0 = blockIdx.x * 64;
  const int l15 = lane & 15, l4 = lane >> 4;
  constexpr int TT = 64 * 4;   // 256 phases (64 ct x 4 k-slabs)

  // ---------- prologue ----------
  float c2v[4];
  #pragma unroll
  for (int cf = 0; cf < 4; ++cf)          // c2 for ct 0
    c2v[cf] = c2g[wc * 64 + cf * 16 + l15];
  #pragma unroll
  for (int it = 0; it < 8; ++it) {        // As: pair-swizzled source
    int p = it * 256 + tid, rA = p >> 5, u = p & 31;
    GLD_LDS16(Xq + (size_t)(row0 + rA) * DIM +
                  ((((u >> 1) ^ (rA & 7)) << 5) | ((u & 1) << 4)),
              &As[0] + p * 16);
  }
  #pragma unroll
  for (int t0 = 0; t0 < 2; ++t0) {        // slabs 0,1 (ct 0, kb = t0*128)
    #pragma unroll
    for (int i = 0; i < 4; ++i) {
      int p = i * 256 + tid, c = p >> 3, u = p & 7;
      GLD_LDS16(Cq + (size_t)c * DIM + t0 * 128 +
                    ((((u >> 1) ^ (c & 3)) << 5) | ((u & 1) << 4)),
                &Bs[t0][0] + p * 16);
    }
  }
  VMW(4);                                  // c2+As+slab0 landed (slab1 flying)
  __builtin_amdgcn_s_barrier();

  i32x8 aF[2][2], bF[2][4];
  #pragma unroll
  for (int rf = 0; rf < 2; ++rf) {        // phase-0 a-frags (kp=0)
    int rA = wr * 32 + rf * 16 + l15;
    int pA = ((l4 ^ (rA & 7)) << 5);
    i32x4 lo = *(const i32x4*)(&As[0] + rA * 512 + pA);
    i32x4 hi = *(const i32x4*)(&As[0] + rA * 512 + pA + 16);
    aF[0][rf] = __builtin_shufflevector(lo, hi, 0, 1, 2, 3, 4, 5, 6, 7);
  }
  #pragma unroll
  for (int cf = 0; cf < 4; ++cf) {        // phase-0 b-frags (slab 0)
    int rB = wc * 64 + cf * 16 + l15;
    int pB = ((l4 ^ (rB & 3)) << 5);
    i32x4 lo = *(const i32x4*)(&Bs[0][0] + rB * 128 + pB);
    i32x4 hi = *(const i32x4*)(&Bs[0][0] + rB * 128 + pB + 16);
    bF[0][cf] = __builtin_shufflevector(lo, hi, 0, 1, 2, 3, 4, 5, 6, 7);
  }

  unsigned b0k[2][4], b1k[2][4], b2k[2][4];
  #pragma unroll
  for (int rf = 0; rf < 2; ++rf)
    #pragma unroll
    for (int rg = 0; rg < 4; ++rg) {
      b0k[rf][rg] = 0xFFFFFFFFu; b1k[rf][rg] = 0xFFFFFFFFu; b2k[rf][rg] = 0xFFFFFFFFu;
    }
  ffrag acc[2][4];
  int slN1 = 1, slN2 = 2;                  // ring-3 cursors: prefetch, stage

  for (int ct = 0; ct < 64; ++ct) {
    #pragma unroll
    for (int kp = 0; kp < 4; ++kp) {
      const int t = ct * 4 + kp;
      asm volatile("s_waitcnt lgkmcnt(0)" ::: "memory");
      __builtin_amdgcn_s_barrier();

      // stage slab t+2
      if (t + 2 < TT) {
        const int ts = t + 2;
        const unsigned char* csrc =
            Cq + (size_t)((ts >> 2) * 128) * DIM + (ts & 3) * 128;
        unsigned char* ldst = &Bs[0][0] + slN2 * 16384;
        #pragma unroll
        for (int i = 0; i < 4; ++i) {
          int p = i * 256 + tid, c = p >> 3, u = p & 7;
          GLD_LDS16(csrc + (size_t)c * DIM +
                        ((((u >> 1) ^ (c & 3)) << 5) | ((u & 1) << 4)),
                    ldst + p * 16);
        }
      }
      if (kp == 0 && ct > 0) {             // c2 for this ct (used at kp==3)
        #pragma unroll
        for (int cf = 0; cf < 4; ++cf)
          c2v[cf] = c2g[ct * 128 + wc * 64 + cf * 16 + l15];
      }

      // counted vmcnt: slab t+1 (staged at t-1) proven landed
      if (t >= TT - 2)              { VMW(0); }
      else if (kp == 0 && ct > 0)   { VMW(8); }   // + 4 c2 loads this phase
      else                          { VMW(4); }

      // frag prefetch t+1 (lands under this phase's MFMAs)
      if (t + 1 < TT) {
        const int kpn = (kp + 1) & 3, bn = (kp + 1) & 1;
        const unsigned char* bsl = &Bs[0][0] + slN1 * 16384;
        #pragma unroll
        for (int rf = 0; rf < 2; ++rf) {
          int rA = wr * 32 + rf * 16 + l15;
          int pA = (((kpn * 4 + l4) ^ (rA & 7)) << 5);
          i32x4 lo = *(const i32x4*)(&As[0] + rA * 512 + pA);
          i32x4 hi = *(const i32x4*)(&As[0] + rA * 512 + pA + 16);
          aF[bn][rf] = __builtin_shufflevector(lo, hi, 0, 1, 2, 3, 4, 5, 6, 7);
        }
        #pragma unroll
        for (int cf = 0; cf < 4; ++cf) {
          int rB = wc * 64 + cf * 16 + l15;
          int pB = ((l4 ^ (rB & 3)) << 5);
          i32x4 lo = *(const i32x4*)(bsl + rB * 128 + pB);
          i32x4 hi = *(const i32x4*)(bsl + rB * 128 + pB + 16);
          bF[bn][cf] = __builtin_shufflevector(lo, hi, 0, 1, 2, 3, 4, 5, 6, 7);
        }
      }

      // MX MFMA, scale = 1.0 (0x7F bytes), fmt fp8-e4m3 both operands
      #pragma unroll
      for (int rf = 0; rf < 2; ++rf)
        #pragma unroll
        for (int cf = 0; cf < 4; ++cf) {
          if (kp == 0) {
            ffrag z = {0.f, 0.f, 0.f, 0.f};
            acc[rf][cf] = __builtin_amdgcn_mfma_scale_f32_16x16x128_f8f6f4(
                aF[0][rf], bF[0][cf], z, 0, 0, 0, 0x7F7F7F7F, 0, 0x7F7F7F7F);
          } else {
            acc[rf][cf] = __builtin_amdgcn_mfma_scale_f32_16x16x128_f8f6f4(
                aF[kp & 1][rf], bF[kp & 1][cf], acc[rf][cf],
                0, 0, 0, 0x7F7F7F7F, 0, 0x7F7F7F7F);
          }
        }

      if (kp == 3) {   // per-ct epilogue: insert all 4 cf keys into best-3
        #pragma unroll
        for (int rf = 0; rf < 2; ++rf)
          #pragma unroll
          for (int rg = 0; rg < 4; ++rg) {
            #pragma unroll
            for (int cf = 0; cf < 4; ++cf) {
              float d = fmaf(-2.0f, acc[rf][cf][rg], c2v[cf] + 2048.0f);
              unsigned k = (__float_as_uint(d) & 0xFFFFFF00u) |
                           (unsigned)((ct << 2) | cf);   // ct<64 -> 8 bits
              unsigned lo0 = min(b0k[rf][rg], k), hi0 = max(b0k[rf][rg], k);
              b0k[rf][rg] = lo0;
              unsigned lo1 = min(b1k[rf][rg], hi0), hi1 = max(b1k[rf][rg], hi0);
              b1k[rf][rg] = lo1;
              b2k[rf][rg] = min(b2k[rf][rg], hi1);
            }
          }
      }
      // rotate ring cursors
      slN1 = slN2;
      slN2 = (slN2 == 2) ? 0 : slN2 + 1;
    }  // kp
  }    // ct

  asm volatile("s_waitcnt lgkmcnt(0)" ::: "memory");
  VMW(0);
  __builtin_amdgcn_s_barrier();

  // per-row min across 16 l15-lanes; cross-wc merge via LDS (overlay on Bs)
  unsigned* dstar = (unsigned*)&Bs[0][0];   // [2][64]
  unsigned gmin[2][4];
  #pragma unroll
  for (int rf = 0; rf < 2; ++rf)
    #pragma unroll
    for (int rg = 0; rg < 4; ++rg) {
      unsigned g = b0k[rf][rg];
      #pragma unroll
      for (int m = 1; m < 16; m <<= 1)
        g = min(g, (unsigned)__shfl_xor((int)g, m, 64));
      gmin[rf][rg] = g;
      if (l15 == 0) dstar[wc * 64 + wr * 32 + rf * 16 + l4 * 4 + rg] = g;
    }
  __syncthreads();
  #pragma unroll
  for (int rf = 0; rf < 2; ++rf)
    #pragma unroll
    for (int rg = 0; rg < 4; ++rg) {
      int rl = wr * 32 + rf * 16 + l4 * 4 + rg;
      unsigned gg = min(gmin[rf][rg], dstar[(wc ^ 1) * 64 + rl]);
      float ds = __uint_as_float(gg & 0xFFFFFF00u);
      unsigned thr = __float_as_uint(ds + MARGIN);
      int base = (row0 + rl) * 96 + wc * 48 + l15 * 3;
      unsigned kk0 = b0k[rf][rg], kk1 = b1k[rf][rg], kk2 = b2k[rf][rg];
      int c0 = (int)((kk0 >> 2) & 63u) * 128 + wc * 64 + (int)(kk0 & 3u) * 16 + l15;
      int c1 = (int)((kk1 >> 2) & 63u) * 128 + wc * 64 + (int)(kk1 & 3u) * 16 + l15;
      int c2i = (int)((kk2 >> 2) & 63u) * 128 + wc * 64 + (int)(kk2 & 3u) * 16 + l15;
      cand[base + 0] = (kk0 <= thr) ? c0 : -1;
      cand[base + 1] = (kk1 <= thr) ? c1 : -1;
      cand[base + 2] = (kk2 <= thr) ? c2i : -1;
    }
}

// ---- exact fp64 refine over candidate set (one wave per row, 96 slots) -----
__global__ void vq_refine(const float* __restrict__ X, const float* __restrict__ Cb,
                          const int* __restrict__ cand, float* __restrict__ idx_out) {
  int row = (blockIdx.x * blockDim.x + threadIdx.x) >> 6;
  int lane = threadIdx.x & 63;
  if (row >= NTOK) return;
  int cv0 = cand[row * 96 + lane];
  int cv1 = (lane < 32) ? cand[row * 96 + 64 + lane] : -1;
  unsigned long long m0 = __ballot(cv0 >= 0);
  unsigned long long m1 = __ballot(cv1 >= 0);
  if (__popcll(m0) + __popcll(m1) == 1) {
    int idx;
    if (m0) idx = __shfl(cv0, __ffsll(m0) - 1, 64);
    else    idx = __shfl(cv1, __ffsll(m1) - 1, 64);
    if (lane == 0) idx_out[row] = (float)idx;
    return;
  }
  const float4* x4 = (const float4*)(X + (size_t)row * DIM);
  float4 xa = x4[lane * 2], xb = x4[lane * 2 + 1];
  double bestd = 1e300; int besti = 0x7FFFFFFF;
  #pragma unroll
  for (int part = 0; part < 2; ++part) {
    unsigned long long mm = part == 0 ? m0 : m1;
    int cv = part == 0 ? cv0 : cv1;
    while (mm) {
      int src = __ffsll(mm) - 1; mm &= mm - 1;
      int idx = __shfl(cv, src, 64);
      const float4* c4 = (const float4*)(Cb + (size_t)idx * DIM);
      float4 ca = c4[lane * 2], cb = c4[lane * 2 + 1];
      double dt = (double)xa.x*ca.x + (double)xa.y*ca.y + (double)xa.z*ca.z + (double)xa.w*ca.w
                + (double)xb.x*cb.x + (double)xb.y*cb.y + (double)xb.z*cb.z + (double)xb.w*cb.w;
      double cc = (double)ca.x*ca.x + (double)ca.y*ca.y + (double)ca.z*ca.z + (double)ca.w*ca.w
                + (double)cb.x*cb.x + (double)cb.y*cb.y + (double)cb.z*cb.z + (double)cb.w*cb.w;
      double sdist = cc - 2.0 * dt;           // x2 omitted: per-row constant
      #pragma unroll
      for (int off = 32; off; off >>= 1) sdist += __shfl_down(sdist, off, 64);
      if (lane == 0 && (sdist < bestd || (sdist == bestd && idx < besti))) { bestd = sdist; besti = idx; }
    }
  }
  if (lane == 0) idx_out[row] = (float)besti;
}

// ---- final: quantized = inputs (runs LAST; overwrites scratch) -------------
__global__ void vq_copy(const float* __restrict__ in, float* __restrict__ out, int n4) {
  int i = blockIdx.x * blockDim.x + threadIdx.x;
  int st = gridDim.x * blockDim.x;
  const float4* s = (const float4*)in;
  float4* d = (float4*)out;
  for (; i < n4; i += st) d[i] = s[i];
}

extern "C" void kernel_launch(void* const* d_in, const int* in_sizes, int n_in,
                              void* d_out, int out_size, void* d_ws, size_t ws_size,
                              hipStream_t stream) {
  const float* X  = (const float*)d_in[0];
  const float* Cb = (const float*)d_in[1];
  float* out = (float*)d_out;

  unsigned char* Xq   = (unsigned char*)out;                  // [N][512] fp8
  unsigned char* Cq   = (unsigned char*)(out + 4194304);      // [K][512] fp8
  int*           cand = (int*)(out + 5242880);                // [N][96]
  float*         c2   = (float*)d_ws;                         // [K]
  float*         idx_out = out + (size_t)NTOK * DIM;

  vq_prep8<<<KCODES / 4, 256, 0, stream>>>(Cb, Cq, c2, KCODES);
  vq_prep8<<<NTOK / 4, 256, 0, stream>>>(X, Xq, nullptr, NTOK);
  vq_main<<<NTOK / 64, 256, 0, stream>>>(Xq, Cq, c2, cand);
  vq_refine<<<NTOK / 4, 256, 0, stream>>>(X, Cb, cand, idx_out);
  vq_copy<<<2048, 256, 0, stream>>>(X, out, NTOK * DIM / 4);
}

// Round 11
// 277.824 us; speedup vs baseline: 3.5624x; 2.7794x over previous
//
#include <hip/hip_runtime.h>
#include <hip/hip_bf16.h>

// VQ argmin via MX-scaled fp8 (e4m3, scale=1.0) K=128 MFMA filter + exact
// fp64 refine. Round 11: kill the spill by REDUCING DEMAND (attribute route
// failed): single-buffered fragments read at use (~120 live VGPR < 128 cap).
// Also formally-correct staging sync: VMW(4)+lgkmcnt(0) BEFORE each barrier.
// Scratch carved from d_out[0:N*D) (float offsets):
//   Xq  fp8[N][512]   @ 0        (16 MiB)
//   Cq  fp8[K][512]   @ 4194304  ( 4 MiB)
//   cand int[N][96]   @ 5242880  (12 MiB)
// c2 f32[K] in d_ws.

constexpr int NTOK = 32768, DIM = 512, KCODES = 8192;
constexpr float MARGIN = 20.0f;

using ffrag = __attribute__((ext_vector_type(4))) float;   // 4 f32 acc
using i32x4 = __attribute__((ext_vector_type(4))) int;
using i32x8 = __attribute__((ext_vector_type(8))) int;

#define GLD_LDS16(g, l)                                                        \
  __builtin_amdgcn_global_load_lds(                                            \
      (const __attribute__((address_space(1))) void*)(g),                      \
      (__attribute__((address_space(3))) void*)(l), 16, 0, 0)
#define VMW(N) asm volatile("s_waitcnt vmcnt(" #N ")" ::: "memory")

// ---- f32 -> fp8 e4m3fn, explicit RNE ---------------------------------------
__device__ __forceinline__ unsigned char f2e4m3(float x) {
  unsigned u = __float_as_uint(x);
  unsigned s = (u >> 24) & 0x80u;
  float ax = fabsf(x);
  if (ax < 0.015625f) {
    int q = (int)rintf(ax * 512.0f);
    return (unsigned char)(s | (unsigned)q);
  }
  int e = (int)((u >> 23) & 0xFF) - 127;
  float m = __uint_as_float((u & 0x7FFFFFu) | 0x3F800000u);
  int r = (int)rintf(m * 8.0f);
  if (r == 16) { r = 8; ++e; }
  if (e > 8) { e = 8; r = 15; }
  return (unsigned char)(s | ((unsigned)(e + 7) << 3) | (unsigned)(r - 8));
}

// ---- convert fp32 rows -> fp8, optional sum-of-squares ---------------------
__global__ void vq_prep8(const float* __restrict__ src, unsigned char* __restrict__ dst,
                         float* __restrict__ sq, int rows) {
  int w = (blockIdx.x * blockDim.x + threadIdx.x) >> 6;
  int lane = threadIdx.x & 63;
  if (w >= rows) return;
  const float4* r4 = (const float4*)(src + (size_t)w * DIM);
  float4 a = r4[lane * 2], b = r4[lane * 2 + 1];
  union { unsigned char c[8]; uint2 v; } o;
  o.c[0]=f2e4m3(a.x); o.c[1]=f2e4m3(a.y); o.c[2]=f2e4m3(a.z); o.c[3]=f2e4m3(a.w);
  o.c[4]=f2e4m3(b.x); o.c[5]=f2e4m3(b.y); o.c[6]=f2e4m3(b.z); o.c[7]=f2e4m3(b.w);
  *(uint2*)(dst + (size_t)w * DIM + lane * 8) = o.v;
  if (sq != nullptr) {
    float s = a.x*a.x + a.y*a.y + a.z*a.z + a.w*a.w
            + b.x*b.x + b.y*b.y + b.z*b.z + b.w*b.w;
    #pragma unroll
    for (int off = 32; off; off >>= 1) s += __shfl_down(s, off, 64);
    if (lane == 0) sq[w] = s;
  }
}

// ---- fused MX-fp8 K=128 MFMA distance + best-3 + candidate emission --------
// Block: 256 thr (4 waves: wr,wc in {0,1}), 64 rows x FULL 8192 codes.
// As [64][512] pair-swizzled (32B pair-unit ^ (row&7)). Slab ring-3 of
// [128 cols][128 kB], pair-unit ^ (col&3). Lane holds 32 contiguous k-bytes
// at k-block (lane>>4)*32 (one MX scale block per lane; scale bytes = 0x7F).
// Phase protocol: {c2(kp2) | stage(t+2)} -> read frags(t) -> MFMA -> epi ->
// VMW(4) + lgkmcnt(0) + barrier  (stage(t+1) provably landed pre-barrier).
__launch_bounds__(256, 2)
__global__ void vq_main(const unsigned char* __restrict__ Xq,
                        const unsigned char* __restrict__ Cq,
                        const float* __restrict__ c2g, int* __restrict__ cand) {
  __shared__ __align__(16) unsigned char As[64 * 512];     // 32 KiB
  __shared__ __align__(16) unsigned char Bs[3][16384];     // 48 KiB ring-3
  const int tid = threadIdx.x, lane = tid & 63;
  const int wid = tid >> 6, wr = wid >> 1, wc = wid & 1;
  const int row0 = blockIdx.x * 64;
  const int l15 = lane & 15, l4 = lane >> 4;
  constexpr int TT = 64 * 4;   // 256 phases (64 ct x 4 k-slabs)

  // ---------- prologue staging ----------
  #pragma unroll
  for (int it = 0; it < 8; ++it) {        // As: pair-swizzled source
    int p = it * 256 + tid, rA = p >> 5, u = p & 31;
    GLD_LDS16(Xq + (size_t)(row0 + rA) * DIM +
                  ((((u >> 1) ^ (rA & 7)) << 5) | ((u & 1) << 4)),
              &As[0] + p * 16);
  }
  #pragma unroll
  for (int t0 = 0; t0 < 2; ++t0) {        // slabs 0,1 (ct 0, kb = t0*128)
    #pragma unroll
    for (int i = 0; i < 4; ++i) {
      int p = i * 256 + tid, c = p >> 3, u = p & 7;
      GLD_LDS16(Cq + (size_t)c * DIM + t0 * 128 +
                    ((((u >> 1) ^ (c & 3)) << 5) | ((u & 1) << 4)),
                &Bs[t0][0] + p * 16);
    }
  }
  VMW(4);                                  // As + slab0 landed (slab1 flying)
  __builtin_amdgcn_s_barrier();

  unsigned b0k[2][4], b1k[2][4], b2k[2][4];
  #pragma unroll
  for (int rf = 0; rf < 2; ++rf)
    #pragma unroll
    for (int rg = 0; rg < 4; ++rg) {
      b0k[rf][rg] = 0xFFFFFFFFu; b1k[rf][rg] = 0xFFFFFFFFu; b2k[rf][rg] = 0xFFFFFFFFu;
    }
  ffrag acc[2][4];
  float c2v[4];
  int rcur = 0, scur = 2;                  // read slot (t%3), stage slot ((t+2)%3)

  for (int ct = 0; ct < 64; ++ct) {
    #pragma unroll
    for (int kp = 0; kp < 4; ++kp) {
      const int t = ct * 4 + kp;

      // c2 for this ct: issue at kp==2 BEFORE the stage, so end-of-phase
      // VMW(4) retires c2 (and stage(t+1)) while keeping stage(t+2) in flight.
      if (kp == 2) {
        #pragma unroll
        for (int cf = 0; cf < 4; ++cf)
          c2v[cf] = c2g[ct * 128 + wc * 64 + cf * 16 + l15];
      }
      // stage slab t+2 into slot scur (slot was last read at phase t-1;
      // all waves drained those reads before the barrier that started t)
      if (t + 2 < TT) {
        const int ts = t + 2;
        const unsigned char* csrc =
            Cq + (size_t)((ts >> 2) * 128) * DIM + (ts & 3) * 128;
        unsigned char* ldst = &Bs[0][0] + scur * 16384;
        #pragma unroll
        for (int i = 0; i < 4; ++i) {
          int p = i * 256 + tid, c = p >> 3, u = p & 7;
          GLD_LDS16(csrc + (size_t)c * DIM +
                        ((((u >> 1) ^ (c & 3)) << 5) | ((u & 1) << 4)),
                    ldst + p * 16);
        }
      }

      // read THIS phase's fragments (slot rcur; landed pre-barrier last phase)
      i32x8 aF[2], bF[4];
      {
        const unsigned char* bsl = &Bs[0][0] + rcur * 16384;
        #pragma unroll
        for (int rf = 0; rf < 2; ++rf) {
          int rA = wr * 32 + rf * 16 + l15;
          int pA = (((kp * 4 + l4) ^ (rA & 7)) << 5);
          i32x4 lo = *(const i32x4*)(&As[0] + rA * 512 + pA);
          i32x4 hi = *(const i32x4*)(&As[0] + rA * 512 + pA + 16);
          aF[rf] = __builtin_shufflevector(lo, hi, 0, 1, 2, 3, 4, 5, 6, 7);
        }
        #pragma unroll
        for (int cf = 0; cf < 4; ++cf) {
          int rB = wc * 64 + cf * 16 + l15;
          int pB = ((l4 ^ (rB & 3)) << 5);
          i32x4 lo = *(const i32x4*)(bsl + rB * 128 + pB);
          i32x4 hi = *(const i32x4*)(bsl + rB * 128 + pB + 16);
          bF[cf] = __builtin_shufflevector(lo, hi, 0, 1, 2, 3, 4, 5, 6, 7);
        }
      }

      // MX MFMA, scale = 1.0 (0x7F bytes), fmt fp8-e4m3 both operands
      #pragma unroll
      for (int rf = 0; rf < 2; ++rf)
        #pragma unroll
        for (int cf = 0; cf < 4; ++cf) {
          if (kp == 0) {
            ffrag z = {0.f, 0.f, 0.f, 0.f};
            acc[rf][cf] = __builtin_amdgcn_mfma_scale_f32_16x16x128_f8f6f4(
                aF[rf], bF[cf], z, 0, 0, 0, 0x7F7F7F7F, 0, 0x7F7F7F7F);
          } else {
            acc[rf][cf] = __builtin_amdgcn_mfma_scale_f32_16x16x128_f8f6f4(
                aF[rf], bF[cf], acc[rf][cf], 0, 0, 0, 0x7F7F7F7F, 0, 0x7F7F7F7F);
          }
        }

      if (kp == 3) {   // per-ct epilogue: insert all 4 cf keys into best-3
        #pragma unroll
        for (int rf = 0; rf < 2; ++rf)
          #pragma unroll
          for (int rg = 0; rg < 4; ++rg) {
            #pragma unroll
            for (int cf = 0; cf < 4; ++cf) {
              float d = fmaf(-2.0f, acc[rf][cf][rg], c2v[cf] + 2048.0f);
              unsigned k = (__float_as_uint(d) & 0xFFFFFF00u) |
                           (unsigned)((ct << 2) | cf);   // ct<64 -> 8 bits
              unsigned lo0 = min(b0k[rf][rg], k), hi0 = max(b0k[rf][rg], k);
              b0k[rf][rg] = lo0;
              unsigned lo1 = min(b1k[rf][rg], hi0), hi1 = max(b1k[rf][rg], hi0);
              b1k[rf][rg] = lo1;
              b2k[rf][rg] = min(b2k[rf][rg], hi1);
            }
          }
      }

      // end-of-phase sync: drain stage(t+1) (next phase's slab) + own ds_reads
      // BEFORE the barrier -> formally race-free slot reuse.
      if (t + 2 < TT) { VMW(4); } else { VMW(0); }
      asm volatile("s_waitcnt lgkmcnt(0)" ::: "memory");
      __builtin_amdgcn_s_barrier();
      int rn = rcur + 1; rcur = (rn == 3) ? 0 : rn;
      int sn = scur + 1; scur = (sn == 3) ? 0 : sn;
    }  // kp
  }    // ct

  // per-row min across 16 l15-lanes; cross-wc merge via LDS (overlay on Bs)
  unsigned* dstar = (unsigned*)&Bs[0][0];   // [2][64]
  unsigned gmin[2][4];
  #pragma unroll
  for (int rf = 0; rf < 2; ++rf)
    #pragma unroll
    for (int rg = 0; rg < 4; ++rg) {
      unsigned g = b0k[rf][rg];
      #pragma unroll
      for (int m = 1; m < 16; m <<= 1)
        g = min(g, (unsigned)__shfl_xor((int)g, m, 64));
      gmin[rf][rg] = g;
      if (l15 == 0) dstar[wc * 64 + wr * 32 + rf * 16 + l4 * 4 + rg] = g;
    }
  __syncthreads();
  #pragma unroll
  for (int rf = 0; rf < 2; ++rf)
    #pragma unroll
    for (int rg = 0; rg < 4; ++rg) {
      int rl = wr * 32 + rf * 16 + l4 * 4 + rg;
      unsigned gg = min(gmin[rf][rg], dstar[(wc ^ 1) * 64 + rl]);
      float ds = __uint_as_float(gg & 0xFFFFFF00u);
      unsigned thr = __float_as_uint(ds + MARGIN);
      int base = (row0 + rl) * 96 + wc * 48 + l15 * 3;
      unsigned kk0 = b0k[rf][rg], kk1 = b1k[rf][rg], kk2 = b2k[rf][rg];
      int c0 = (int)((kk0 >> 2) & 63u) * 128 + wc * 64 + (int)(kk0 & 3u) * 16 + l15;
      int c1 = (int)((kk1 >> 2) & 63u) * 128 + wc * 64 + (int)(kk1 & 3u) * 16 + l15;
      int c2i = (int)((kk2 >> 2) & 63u) * 128 + wc * 64 + (int)(kk2 & 3u) * 16 + l15;
      cand[base + 0] = (kk0 <= thr) ? c0 : -1;
      cand[base + 1] = (kk1 <= thr) ? c1 : -1;
      cand[base + 2] = (kk2 <= thr) ? c2i : -1;
    }
}

// ---- exact fp64 refine over candidate set (one wave per row, 96 slots) -----
__global__ void vq_refine(const float* __restrict__ X, const float* __restrict__ Cb,
                          const int* __restrict__ cand, float* __restrict__ idx_out) {
  int row = (blockIdx.x * blockDim.x + threadIdx.x) >> 6;
  int lane = threadIdx.x & 63;
  if (row >= NTOK) return;
  int cv0 = cand[row * 96 + lane];
  int cv1 = (lane < 32) ? cand[row * 96 + 64 + lane] : -1;
  unsigned long long m0 = __ballot(cv0 >= 0);
  unsigned long long m1 = __ballot(cv1 >= 0);
  if (__popcll(m0) + __popcll(m1) == 1) {
    int idx;
    if (m0) idx = __shfl(cv0, __ffsll(m0) - 1, 64);
    else    idx = __shfl(cv1, __ffsll(m1) - 1, 64);
    if (lane == 0) idx_out[row] = (float)idx;
    return;
  }
  const float4* x4 = (const float4*)(X + (size_t)row * DIM);
  float4 xa = x4[lane * 2], xb = x4[lane * 2 + 1];
  double bestd = 1e300; int besti = 0x7FFFFFFF;
  #pragma unroll
  for (int part = 0; part < 2; ++part) {
    unsigned long long mm = part == 0 ? m0 : m1;
    int cv = part == 0 ? cv0 : cv1;
    while (mm) {
      int src = __ffsll(mm) - 1; mm &= mm - 1;
      int idx = __shfl(cv, src, 64);
      const float4* c4 = (const float4*)(Cb + (size_t)idx * DIM);
      float4 ca = c4[lane * 2], cb = c4[lane * 2 + 1];
      double dt = (double)xa.x*ca.x + (double)xa.y*ca.y + (double)xa.z*ca.z + (double)xa.w*ca.w
                + (double)xb.x*cb.x + (double)xb.y*cb.y + (double)xb.z*cb.z + (double)xb.w*cb.w;
      double cc = (double)ca.x*ca.x + (double)ca.y*ca.y + (double)ca.z*ca.z + (double)ca.w*ca.w
                + (double)cb.x*cb.x + (double)cb.y*cb.y + (double)cb.z*cb.z + (double)cb.w*cb.w;
      double sdist = cc - 2.0 * dt;           // x2 omitted: per-row constant
      #pragma unroll
      for (int off = 32; off; off >>= 1) sdist += __shfl_down(sdist, off, 64);
      if (lane == 0 && (sdist < bestd || (sdist == bestd && idx < besti))) { bestd = sdist; besti = idx; }
    }
  }
  if (lane == 0) idx_out[row] = (float)besti;
}

// ---- final: quantized = inputs (runs LAST; overwrites scratch) -------------
__global__ void vq_copy(const float* __restrict__ in, float* __restrict__ out, int n4) {
  int i = blockIdx.x * blockDim.x + threadIdx.x;
  int st = gridDim.x * blockDim.x;
  const float4* s = (const float4*)in;
  float4* d = (float4*)out;
  for (; i < n4; i += st) d[i] = s[i];
}

extern "C" void kernel_launch(void* const* d_in, const int* in_sizes, int n_in,
                              void* d_out, int out_size, void* d_ws, size_t ws_size,
                              hipStream_t stream) {
  const float* X  = (const float*)d_in[0];
  const float* Cb = (const float*)d_in[1];
  float* out = (float*)d_out;

  unsigned char* Xq   = (unsigned char*)out;                  // [N][512] fp8
  unsigned char* Cq   = (unsigned char*)(out + 4194304);      // [K][512] fp8
  int*           cand = (int*)(out + 5242880);                // [N][96]
  float*         c2   = (float*)d_ws;                         // [K]
  float*         idx_out = out + (size_t)NTOK * DIM;

  vq_prep8<<<KCODES / 4, 256, 0, stream>>>(Cb, Cq, c2, KCODES);
  vq_prep8<<<NTOK / 4, 256, 0, stream>>>(X, Xq, nullptr, NTOK);
  vq_main<<<NTOK / 64, 256, 0, stream>>>(Xq, Cq, c2, cand);
  vq_refine<<<NTOK / 4, 256, 0, stream>>>(X, Cb, cand, idx_out);
  vq_copy<<<2048, 256, 0, stream>>>(X, out, NTOK * DIM / 4);
}

// Round 12
// 275.014 us; speedup vs baseline: 3.5988x; 1.0102x over previous
//
#include <hip/hip_runtime.h>
#include <hip/hip_bf16.h>

// VQ argmin via MX-scaled fp8 (e4m3, scale=1.0) K=128 MFMA filter + exact
// fp64 refine. Round 12: kill the 4-way LDS bank conflicts (384 cyc/phase).
// Old 32B-pair XOR swizzle only spread fragments over 4 of 8 bank-groups;
// new 16B-unit XOR (u ^= row&7, 3 bits) spreads each b128 over all 8 groups
// -> 2-way (free, m136). Same involution on global_load_lds SOURCE (LDS dest
// stays linear, rule #21) and on the read side. Everything else == round 11.
// Scratch carved from d_out[0:N*D) (float offsets):
//   Xq  fp8[N][512]   @ 0        (16 MiB)
//   Cq  fp8[K][512]   @ 4194304  ( 4 MiB)
//   cand int[N][96]   @ 5242880  (12 MiB)
// c2 f32[K] in d_ws.

constexpr int NTOK = 32768, DIM = 512, KCODES = 8192;
constexpr float MARGIN = 20.0f;

using ffrag = __attribute__((ext_vector_type(4))) float;   // 4 f32 acc
using i32x4 = __attribute__((ext_vector_type(4))) int;
using i32x8 = __attribute__((ext_vector_type(8))) int;

#define GLD_LDS16(g, l)                                                        \
  __builtin_amdgcn_global_load_lds(                                            \
      (const __attribute__((address_space(1))) void*)(g),                      \
      (__attribute__((address_space(3))) void*)(l), 16, 0, 0)
#define VMW(N) asm volatile("s_waitcnt vmcnt(" #N ")" ::: "memory")

// ---- f32 -> fp8 e4m3fn, explicit RNE ---------------------------------------
__device__ __forceinline__ unsigned char f2e4m3(float x) {
  unsigned u = __float_as_uint(x);
  unsigned s = (u >> 24) & 0x80u;
  float ax = fabsf(x);
  if (ax < 0.015625f) {
    int q = (int)rintf(ax * 512.0f);
    return (unsigned char)(s | (unsigned)q);
  }
  int e = (int)((u >> 23) & 0xFF) - 127;
  float m = __uint_as_float((u & 0x7FFFFFu) | 0x3F800000u);
  int r = (int)rintf(m * 8.0f);
  if (r == 16) { r = 8; ++e; }
  if (e > 8) { e = 8; r = 15; }
  return (unsigned char)(s | ((unsigned)(e + 7) << 3) | (unsigned)(r - 8));
}

// ---- convert fp32 rows -> fp8, optional sum-of-squares ---------------------
__global__ void vq_prep8(const float* __restrict__ src, unsigned char* __restrict__ dst,
                         float* __restrict__ sq, int rows) {
  int w = (blockIdx.x * blockDim.x + threadIdx.x) >> 6;
  int lane = threadIdx.x & 63;
  if (w >= rows) return;
  const float4* r4 = (const float4*)(src + (size_t)w * DIM);
  float4 a = r4[lane * 2], b = r4[lane * 2 + 1];
  union { unsigned char c[8]; uint2 v; } o;
  o.c[0]=f2e4m3(a.x); o.c[1]=f2e4m3(a.y); o.c[2]=f2e4m3(a.z); o.c[3]=f2e4m3(a.w);
  o.c[4]=f2e4m3(b.x); o.c[5]=f2e4m3(b.y); o.c[6]=f2e4m3(b.z); o.c[7]=f2e4m3(b.w);
  *(uint2*)(dst + (size_t)w * DIM + lane * 8) = o.v;
  if (sq != nullptr) {
    float s = a.x*a.x + a.y*a.y + a.z*a.z + a.w*a.w
            + b.x*b.x + b.y*b.y + b.z*b.z + b.w*b.w;
    #pragma unroll
    for (int off = 32; off; off >>= 1) s += __shfl_down(s, off, 64);
    if (lane == 0) sq[w] = s;
  }
}

// ---- fused MX-fp8 K=128 MFMA distance + best-3 + candidate emission --------
// Block: 256 thr (4 waves: wr,wc in {0,1}), 64 rows x FULL 8192 codes.
// As [64 rows][32 units of 16B], unit stored at u^(row&7). Slab ring-3 of
// [128 cols][8 units of 16B], unit stored at u^(col&7). Lane's 32 logical
// k-bytes (one MX scale block) = units 2j, 2j+1 -> two b128 reads, each
// spread across all 8 bank-groups over l15 (2-way, free).
__launch_bounds__(256, 2)
__global__ void vq_main(const unsigned char* __restrict__ Xq,
                        const unsigned char* __restrict__ Cq,
                        const float* __restrict__ c2g, int* __restrict__ cand) {
  __shared__ __align__(16) unsigned char As[64 * 512];     // 32 KiB
  __shared__ __align__(16) unsigned char Bs[3][16384];     // 48 KiB ring-3
  const int tid = threadIdx.x, lane = tid & 63;
  const int wid = tid >> 6, wr = wid >> 1, wc = wid & 1;
  const int row0 = blockIdx.x * 64;
  const int l15 = lane & 15, l4 = lane >> 4;
  constexpr int TT = 64 * 4;   // 256 phases (64 ct x 4 k-slabs)

  // ---------- prologue staging ----------
  #pragma unroll
  for (int it = 0; it < 8; ++it) {        // As: 16B-unit swizzled source
    int p = it * 256 + tid, rA = p >> 5, u = p & 31;
    GLD_LDS16(Xq + (size_t)(row0 + rA) * DIM + ((u ^ (rA & 7)) << 4),
              &As[0] + p * 16);
  }
  #pragma unroll
  for (int t0 = 0; t0 < 2; ++t0) {        // slabs 0,1 (ct 0, kb = t0*128)
    #pragma unroll
    for (int i = 0; i < 4; ++i) {
      int p = i * 256 + tid, c = p >> 3, u = p & 7;
      GLD_LDS16(Cq + (size_t)c * DIM + t0 * 128 + ((u ^ (c & 7)) << 4),
                &Bs[t0][0] + p * 16);
    }
  }
  VMW(4);                                  // As + slab0 landed (slab1 flying)
  __builtin_amdgcn_s_barrier();

  unsigned b0k[2][4], b1k[2][4], b2k[2][4];
  #pragma unroll
  for (int rf = 0; rf < 2; ++rf)
    #pragma unroll
    for (int rg = 0; rg < 4; ++rg) {
      b0k[rf][rg] = 0xFFFFFFFFu; b1k[rf][rg] = 0xFFFFFFFFu; b2k[rf][rg] = 0xFFFFFFFFu;
    }
  ffrag acc[2][4];
  float c2v[4];
  int rcur = 0, scur = 2;                  // read slot (t%3), stage slot ((t+2)%3)

  for (int ct = 0; ct < 64; ++ct) {
    #pragma unroll
    for (int kp = 0; kp < 4; ++kp) {
      const int t = ct * 4 + kp;

      // c2 for this ct: issue at kp==2 BEFORE the stage, so end-of-phase
      // VMW(4) retires c2 (and stage(t+1)) while keeping stage(t+2) in flight.
      if (kp == 2) {
        #pragma unroll
        for (int cf = 0; cf < 4; ++cf)
          c2v[cf] = c2g[ct * 128 + wc * 64 + cf * 16 + l15];
      }
      // stage slab t+2 into slot scur (slot was last read at phase t-1;
      // all waves drained those reads before the barrier that started t)
      if (t + 2 < TT) {
        const int ts = t + 2;
        const unsigned char* csrc =
            Cq + (size_t)((ts >> 2) * 128) * DIM + (ts & 3) * 128;
        unsigned char* ldst = &Bs[0][0] + scur * 16384;
        #pragma unroll
        for (int i = 0; i < 4; ++i) {
          int p = i * 256 + tid, c = p >> 3, u = p & 7;
          GLD_LDS16(csrc + (size_t)c * DIM + ((u ^ (c & 7)) << 4),
                    ldst + p * 16);
        }
      }

      // read THIS phase's fragments (slot rcur; landed pre-barrier last phase)
      i32x8 aF[2], bF[4];
      {
        const unsigned char* bsl = &Bs[0][0] + rcur * 16384;
        #pragma unroll
        for (int rf = 0; rf < 2; ++rf) {
          int rA = wr * 32 + rf * 16 + l15;
          int sw = rA & 7, j2 = (kp * 4 + l4) * 2;
          i32x4 lo = *(const i32x4*)(&As[0] + rA * 512 + ((j2 ^ sw) << 4));
          i32x4 hi = *(const i32x4*)(&As[0] + rA * 512 + (((j2 + 1) ^ sw) << 4));
          aF[rf] = __builtin_shufflevector(lo, hi, 0, 1, 2, 3, 4, 5, 6, 7);
        }
        #pragma unroll
        for (int cf = 0; cf < 4; ++cf) {
          int rB = wc * 64 + cf * 16 + l15;
          int sw = rB & 7, u2 = l4 * 2;
          i32x4 lo = *(const i32x4*)(bsl + rB * 128 + ((u2 ^ sw) << 4));
          i32x4 hi = *(const i32x4*)(bsl + rB * 128 + (((u2 + 1) ^ sw) << 4));
          bF[cf] = __builtin_shufflevector(lo, hi, 0, 1, 2, 3, 4, 5, 6, 7);
        }
      }

      // MX MFMA, scale = 1.0 (0x7F bytes), fmt fp8-e4m3 both operands
      #pragma unroll
      for (int rf = 0; rf < 2; ++rf)
        #pragma unroll
        for (int cf = 0; cf < 4; ++cf) {
          if (kp == 0) {
            ffrag z = {0.f, 0.f, 0.f, 0.f};
            acc[rf][cf] = __builtin_amdgcn_mfma_scale_f32_16x16x128_f8f6f4(
                aF[rf], bF[cf], z, 0, 0, 0, 0x7F7F7F7F, 0, 0x7F7F7F7F);
          } else {
            acc[rf][cf] = __builtin_amdgcn_mfma_scale_f32_16x16x128_f8f6f4(
                aF[rf], bF[cf], acc[rf][cf], 0, 0, 0, 0x7F7F7F7F, 0, 0x7F7F7F7F);
          }
        }

      if (kp == 3) {   // per-ct epilogue: insert all 4 cf keys into best-3
        #pragma unroll
        for (int rf = 0; rf < 2; ++rf)
          #pragma unroll
          for (int rg = 0; rg < 4; ++rg) {
            #pragma unroll
            for (int cf = 0; cf < 4; ++cf) {
              float d = fmaf(-2.0f, acc[rf][cf][rg], c2v[cf] + 2048.0f);
              unsigned k = (__float_as_uint(d) & 0xFFFFFF00u) |
                           (unsigned)((ct << 2) | cf);   // ct<64 -> 8 bits
              unsigned lo0 = min(b0k[rf][rg], k), hi0 = max(b0k[rf][rg], k);
              b0k[rf][rg] = lo0;
              unsigned lo1 = min(b1k[rf][rg], hi0), hi1 = max(b1k[rf][rg], hi0);
              b1k[rf][rg] = lo1;
              b2k[rf][rg] = min(b2k[rf][rg], hi1);
            }
          }
      }

      // end-of-phase sync: drain stage(t+1) (next phase's slab) + own ds_reads
      // BEFORE the barrier -> formally race-free slot reuse.
      if (t + 2 < TT) { VMW(4); } else { VMW(0); }
      asm volatile("s_waitcnt lgkmcnt(0)" ::: "memory");
      __builtin_amdgcn_s_barrier();
      int rn = rcur + 1; rcur = (rn == 3) ? 0 : rn;
      int sn = scur + 1; scur = (sn == 3) ? 0 : sn;
    }  // kp
  }    // ct

  // per-row min across 16 l15-lanes; cross-wc merge via LDS (overlay on Bs)
  unsigned* dstar = (unsigned*)&Bs[0][0];   // [2][64]
  unsigned gmin[2][4];
  #pragma unroll
  for (int rf = 0; rf < 2; ++rf)
    #pragma unroll
    for (int rg = 0; rg < 4; ++rg) {
      unsigned g = b0k[rf][rg];
      #pragma unroll
      for (int m = 1; m < 16; m <<= 1)
        g = min(g, (unsigned)__shfl_xor((int)g, m, 64));
      gmin[rf][rg] = g;
      if (l15 == 0) dstar[wc * 64 + wr * 32 + rf * 16 + l4 * 4 + rg] = g;
    }
  __syncthreads();
  #pragma unroll
  for (int rf = 0; rf < 2; ++rf)
    #pragma unroll
    for (int rg = 0; rg < 4; ++rg) {
      int rl = wr * 32 + rf * 16 + l4 * 4 + rg;
      unsigned gg = min(gmin[rf][rg], dstar[(wc ^ 1) * 64 + rl]);
      float ds = __uint_as_float(gg & 0xFFFFFF00u);
      unsigned thr = __float_as_uint(ds + MARGIN);
      int base = (row0 + rl) * 96 + wc * 48 + l15 * 3;
      unsigned kk0 = b0k[rf][rg], kk1 = b1k[rf][rg], kk2 = b2k[rf][rg];
      int c0 = (int)((kk0 >> 2) & 63u) * 128 + wc * 64 + (int)(kk0 & 3u) * 16 + l15;
      int c1 = (int)((kk1 >> 2) & 63u) * 128 + wc * 64 + (int)(kk1 & 3u) * 16 + l15;
      int c2i = (int)((kk2 >> 2) & 63u) * 128 + wc * 64 + (int)(kk2 & 3u) * 16 + l15;
      cand[base + 0] = (kk0 <= thr) ? c0 : -1;
      cand[base + 1] = (kk1 <= thr) ? c1 : -1;
      cand[base + 2] = (kk2 <= thr) ? c2i : -1;
    }
}

// ---- exact fp64 refine over candidate set (one wave per row, 96 slots) -----
__global__ void vq_refine(const float* __restrict__ X, const float* __restrict__ Cb,
                          const int* __restrict__ cand, float* __restrict__ idx_out) {
  int row = (blockIdx.x * blockDim.x + threadIdx.x) >> 6;
  int lane = threadIdx.x & 63;
  if (row >= NTOK) return;
  int cv0 = cand[row * 96 + lane];
  int cv1 = (lane < 32) ? cand[row * 96 + 64 + lane] : -1;
  unsigned long long m0 = __ballot(cv0 >= 0);
  unsigned long long m1 = __ballot(cv1 >= 0);
  if (__popcll(m0) + __popcll(m1) == 1) {
    int idx;
    if (m0) idx = __shfl(cv0, __ffsll(m0) - 1, 64);
    else    idx = __shfl(cv1, __ffsll(m1) - 1, 64);
    if (lane == 0) idx_out[row] = (float)idx;
    return;
  }
  const float4* x4 = (const float4*)(X + (size_t)row * DIM);
  float4 xa = x4[lane * 2], xb = x4[lane * 2 + 1];
  double bestd = 1e300; int besti = 0x7FFFFFFF;
  #pragma unroll
  for (int part = 0; part < 2; ++part) {
    unsigned long long mm = part == 0 ? m0 : m1;
    int cv = part == 0 ? cv0 : cv1;
    while (mm) {
      int src = __ffsll(mm) - 1; mm &= mm - 1;
      int idx = __shfl(cv, src, 64);
      const float4* c4 = (const float4*)(Cb + (size_t)idx * DIM);
      float4 ca = c4[lane * 2], cb = c4[lane * 2 + 1];
      double dt = (double)xa.x*ca.x + (double)xa.y*ca.y + (double)xa.z*ca.z + (double)xa.w*ca.w
                + (double)xb.x*cb.x + (double)xb.y*cb.y + (double)xb.z*cb.z + (double)xb.w*cb.w;
      double cc = (double)ca.x*ca.x + (double)ca.y*ca.y + (double)ca.z*ca.z + (double)ca.w*ca.w
                + (double)cb.x*cb.x + (double)cb.y*cb.y + (double)cb.z*cb.z + (double)cb.w*cb.w;
      double sdist = cc - 2.0 * dt;           // x2 omitted: per-row constant
      #pragma unroll
      for (int off = 32; off; off >>= 1) sdist += __shfl_down(sdist, off, 64);
      if (lane == 0 && (sdist < bestd || (sdist == bestd && idx < besti))) { bestd = sdist; besti = idx; }
    }
  }
  if (lane == 0) idx_out[row] = (float)besti;
}

// ---- final: quantized = inputs (runs LAST; overwrites scratch) -------------
__global__ void vq_copy(const float* __restrict__ in, float* __restrict__ out, int n4) {
  int i = blockIdx.x * blockDim.x + threadIdx.x;
  int st = gridDim.x * blockDim.x;
  const float4* s = (const float4*)in;
  float4* d = (float4*)out;
  for (; i < n4; i += st) d[i] = s[i];
}

extern "C" void kernel_launch(void* const* d_in, const int* in_sizes, int n_in,
                              void* d_out, int out_size, void* d_ws, size_t ws_size,
                              hipStream_t stream) {
  const float* X  = (const float*)d_in[0];
  const float* Cb = (const float*)d_in[1];
  float* out = (float*)d_out;

  unsigned char* Xq   = (unsigned char*)out;                  // [N][512] fp8
  unsigned char* Cq   = (unsigned char*)(out + 4194304);      // [K][512] fp8
  int*           cand = (int*)(out + 5242880);                // [N][96]
  float*         c2   = (float*)d_ws;                         // [K]
  float*         idx_out = out + (size_t)NTOK * DIM;

  vq_prep8<<<KCODES / 4, 256, 0, stream>>>(Cb, Cq, c2, KCODES);
  vq_prep8<<<NTOK / 4, 256, 0, stream>>>(X, Xq, nullptr, NTOK);
  vq_main<<<NTOK / 64, 256, 0, stream>>>(Xq, Cq, c2, cand);
  vq_refine<<<NTOK / 4, 256, 0, stream>>>(X, Cb, cand, idx_out);
  vq_copy<<<2048, 256, 0, stream>>>(X, out, NTOK * DIM / 4);
}

// Round 13
// 247.832 us; speedup vs baseline: 3.9936x; 1.1097x over previous
//
#include <hip/hip_runtime.h>
#include <hip/hip_bf16.h>

// VQ argmin via MX-scaled fp8 (e4m3, scale=1.0) K=128 MFMA filter + exact
// fp64 refine. Round 13: kill per-phase VALU (42% busy) — 12-phase macro
// unroll (lcm of kp-period 4, ring-period 3) makes every LDS address
// base+compile-time-imm; stage source advances by static strides; s_setprio
// around the MFMA cluster (T5). Sync protocol identical to rounds 11/12.
// Scratch carved from d_out[0:N*D) (float offsets):
//   Xq  fp8[N][512]   @ 0        (16 MiB)
//   Cq  fp8[K][512]   @ 4194304  ( 4 MiB)
//   cand int[N][96]   @ 5242880  (12 MiB)
// c2 f32[K] in d_ws.

constexpr int NTOK = 32768, DIM = 512, KCODES = 8192;
constexpr float MARGIN = 20.0f;

using ffrag = __attribute__((ext_vector_type(4))) float;   // 4 f32 acc
using i32x4 = __attribute__((ext_vector_type(4))) int;
using i32x8 = __attribute__((ext_vector_type(8))) int;

#define GLD_LDS16(g, l)                                                        \
  __builtin_amdgcn_global_load_lds(                                            \
      (const __attribute__((address_space(1))) void*)(g),                      \
      (__attribute__((address_space(3))) void*)(l), 16, 0, 0)
#define VMW(N) asm volatile("s_waitcnt vmcnt(" #N ")" ::: "memory")

// ---- f32 -> fp8 e4m3fn, explicit RNE ---------------------------------------
__device__ __forceinline__ unsigned char f2e4m3(float x) {
  unsigned u = __float_as_uint(x);
  unsigned s = (u >> 24) & 0x80u;
  float ax = fabsf(x);
  if (ax < 0.015625f) {
    int q = (int)rintf(ax * 512.0f);
    return (unsigned char)(s | (unsigned)q);
  }
  int e = (int)((u >> 23) & 0xFF) - 127;
  float m = __uint_as_float((u & 0x7FFFFFu) | 0x3F800000u);
  int r = (int)rintf(m * 8.0f);
  if (r == 16) { r = 8; ++e; }
  if (e > 8) { e = 8; r = 15; }
  return (unsigned char)(s | ((unsigned)(e + 7) << 3) | (unsigned)(r - 8));
}

// ---- convert fp32 rows -> fp8, optional sum-of-squares ---------------------
__global__ void vq_prep8(const float* __restrict__ src, unsigned char* __restrict__ dst,
                         float* __restrict__ sq, int rows) {
  int w = (blockIdx.x * blockDim.x + threadIdx.x) >> 6;
  int lane = threadIdx.x & 63;
  if (w >= rows) return;
  const float4* r4 = (const float4*)(src + (size_t)w * DIM);
  float4 a = r4[lane * 2], b = r4[lane * 2 + 1];
  union { unsigned char c[8]; uint2 v; } o;
  o.c[0]=f2e4m3(a.x); o.c[1]=f2e4m3(a.y); o.c[2]=f2e4m3(a.z); o.c[3]=f2e4m3(a.w);
  o.c[4]=f2e4m3(b.x); o.c[5]=f2e4m3(b.y); o.c[6]=f2e4m3(b.z); o.c[7]=f2e4m3(b.w);
  *(uint2*)(dst + (size_t)w * DIM + lane * 8) = o.v;
  if (sq != nullptr) {
    float s = a.x*a.x + a.y*a.y + a.z*a.z + a.w*a.w
            + b.x*b.x + b.y*b.y + b.z*b.z + b.w*b.w;
    #pragma unroll
    for (int off = 32; off; off >>= 1) s += __shfl_down(s, off, 64);
    if (lane == 0) sq[w] = s;
  }
}

// ---- fused MX-fp8 K=128 MFMA distance + best-3 + candidate emission --------
// Block: 256 thr (4 waves: wr,wc in {0,1}), 64 rows x FULL 8192 codes.
// As [64 rows][32 units], unit stored at u^(row&7). Slab ring-3 of
// [128 cols][8 units], unit stored at u^(col&7). Phase protocol == r11/r12:
// {c2(kp2) | stage(t+2)} -> read frags(t) -> MFMA -> epi -> VMW(4)+lgkm(0)
// -> barrier. 12-phase unroll makes slots/kp compile-time.
__launch_bounds__(256, 2)
__global__ void vq_main(const unsigned char* __restrict__ Xq,
                        const unsigned char* __restrict__ Cq,
                        const float* __restrict__ c2g, int* __restrict__ cand) {
  __shared__ __align__(16) unsigned char As[64 * 512];     // 32 KiB
  __shared__ __align__(16) unsigned char Bs[3][16384];     // 48 KiB ring-3
  const int tid = threadIdx.x, lane = tid & 63;
  const int wid = tid >> 6, wr = wid >> 1, wc = wid & 1;
  const int row0 = blockIdx.x * 64;
  const int l15 = lane & 15, l4 = lane >> 4;

  // ---------- prologue staging (slabs ts=0,1 into slots 0,1) ----------
  #pragma unroll
  for (int it = 0; it < 8; ++it) {        // As: 16B-unit swizzled source
    int p = it * 256 + tid, rA = p >> 5, u = p & 31;
    GLD_LDS16(Xq + (size_t)(row0 + rA) * DIM + ((u ^ (rA & 7)) << 4),
              &As[0] + p * 16);
  }
  #pragma unroll
  for (int t0 = 0; t0 < 2; ++t0) {
    #pragma unroll
    for (int i = 0; i < 4; ++i) {
      int p = i * 256 + tid, c = p >> 3, u = p & 7;
      GLD_LDS16(Cq + (size_t)c * DIM + t0 * 128 + ((u ^ (c & 7)) << 4),
                &Bs[t0][0] + p * 16);
    }
  }
  VMW(4);                                  // As + slab0 landed (slab1 flying)
  __builtin_amdgcn_s_barrier();

  // ---------- hoisted per-thread address state ----------
  int aLo[2], aHi[2];
  #pragma unroll
  for (int rf = 0; rf < 2; ++rf) {
    int rA = wr * 32 + rf * 16 + l15, sw = rA & 7;
    aLo[rf] = rA * 512 + (((2 * l4) ^ sw) << 4);
    aHi[rf] = rA * 512 + (((2 * l4 + 1) ^ sw) << 4);
  }
  int bLo[4], bHi[4];
  #pragma unroll
  for (int cf = 0; cf < 4; ++cf) {
    int rB = wc * 64 + cf * 16 + l15, sw = rB & 7;
    bLo[cf] = rB * 128 + (((2 * l4) ^ sw) << 4);
    bHi[cf] = rB * 128 + (((2 * l4 + 1) ^ sw) << 4);
  }
  const int cS = tid >> 3, uS = tid & 7;
  const unsigned char* gsrc = Cq + cS * 512 + ((uS ^ (cS & 7)) << 4) + 256; // ts=2
  const float* c2p = c2g + wc * 64 + l15;
  unsigned char* ldst = &Bs[0][0] + tid * 16;
  const unsigned char* AsP = &As[0];
  const unsigned char* BsP = &Bs[0][0];

  unsigned b0k[2][4], b1k[2][4], b2k[2][4];
  #pragma unroll
  for (int rf = 0; rf < 2; ++rf)
    #pragma unroll
    for (int rg = 0; rg < 4; ++rg) {
      b0k[rf][rg] = 0xFFFFFFFFu; b1k[rf][rg] = 0xFFFFFFFFu; b2k[rf][rg] = 0xFFFFFFFFu;
    }
  ffrag acc[2][4];
  float c2v[4];

// One phase. KP/RS/SS/GSTEP/VMN are literals; CT is a runtime int.
#define PH(KP, RS, SS, CT, STG, GSTEP, VMN)                                    \
  {                                                                            \
    if (KP == 2) {                                                             \
      c2v[0] = c2p[0];  c2v[1] = c2p[16];                                      \
      c2v[2] = c2p[32]; c2v[3] = c2p[48];                                      \
      c2p += 128;                                                              \
    }                                                                          \
    if (STG) {                                                                 \
      GLD_LDS16(gsrc,         ldst + (SS) * 16384 + 0);                        \
      GLD_LDS16(gsrc + 16384, ldst + (SS) * 16384 + 4096);                     \
      GLD_LDS16(gsrc + 32768, ldst + (SS) * 16384 + 8192);                     \
      GLD_LDS16(gsrc + 49152, ldst + (SS) * 16384 + 12288);                    \
      gsrc += (GSTEP);                                                         \
    }                                                                          \
    i32x8 aF[2], bF[4];                                                        \
    _Pragma("unroll")                                                          \
    for (int rf = 0; rf < 2; ++rf) {                                           \
      i32x4 lo = *(const i32x4*)(AsP + aLo[rf] + (KP) * 128);                  \
      i32x4 hi = *(const i32x4*)(AsP + aHi[rf] + (KP) * 128);                  \
      aF[rf] = __builtin_shufflevector(lo, hi, 0, 1, 2, 3, 4, 5, 6, 7);        \
    }                                                                          \
    _Pragma("unroll")                                                          \
    for (int cf = 0; cf < 4; ++cf) {                                           \
      i32x4 lo = *(const i32x4*)(BsP + (RS) * 16384 + bLo[cf]);                \
      i32x4 hi = *(const i32x4*)(BsP + (RS) * 16384 + bHi[cf]);                \
      bF[cf] = __builtin_shufflevector(lo, hi, 0, 1, 2, 3, 4, 5, 6, 7);        \
    }                                                                          \
    __builtin_amdgcn_s_setprio(1);                                             \
    _Pragma("unroll")                                                          \
    for (int rf = 0; rf < 2; ++rf)                                             \
      _Pragma("unroll")                                                        \
      for (int cf = 0; cf < 4; ++cf) {                                         \
        if (KP == 0) {                                                         \
          ffrag z = {0.f, 0.f, 0.f, 0.f};                                      \
          acc[rf][cf] = __builtin_amdgcn_mfma_scale_f32_16x16x128_f8f6f4(      \
              aF[rf], bF[cf], z, 0, 0, 0, 0x7F7F7F7F, 0, 0x7F7F7F7F);          \
        } else {                                                               \
          acc[rf][cf] = __builtin_amdgcn_mfma_scale_f32_16x16x128_f8f6f4(      \
              aF[rf], bF[cf], acc[rf][cf], 0, 0, 0, 0x7F7F7F7F, 0,             \
              0x7F7F7F7F);                                                     \
        }                                                                      \
      }                                                                        \
    __builtin_amdgcn_s_setprio(0);                                             \
    if (KP == 3) {                                                             \
      _Pragma("unroll")                                                        \
      for (int rf = 0; rf < 2; ++rf)                                           \
        _Pragma("unroll")                                                      \
        for (int rg = 0; rg < 4; ++rg) {                                       \
          _Pragma("unroll")                                                    \
          for (int cf = 0; cf < 4; ++cf) {                                     \
            float d = fmaf(-2.0f, acc[rf][cf][rg], c2v[cf] + 2048.0f);         \
            unsigned k = (__float_as_uint(d) & 0xFFFFFF00u) |                  \
                         (unsigned)(((CT) << 2) | cf);                         \
            unsigned lo0 = min(b0k[rf][rg], k), hi0 = max(b0k[rf][rg], k);     \
            b0k[rf][rg] = lo0;                                                 \
            unsigned lo1 = min(b1k[rf][rg], hi0), hi1 = max(b1k[rf][rg], hi0); \
            b1k[rf][rg] = lo1;                                                 \
            b2k[rf][rg] = min(b2k[rf][rg], hi1);                               \
          }                                                                    \
        }                                                                      \
    }                                                                          \
    VMW(VMN);                                                                  \
    asm volatile("s_waitcnt lgkmcnt(0)" ::: "memory");                         \
    __builtin_amdgcn_s_barrier();                                              \
  }

  // main loop: 21 x 12 phases (3 cts each); slot/kp pattern period = 12
  for (int c3 = 0; c3 < 21; ++c3) {
    const int ct0 = c3 * 3;
    PH(0, 0, 2, ct0,     1, 128,   4)
    PH(1, 1, 0, ct0,     1, 65152, 4)
    PH(2, 2, 1, ct0,     1, 128,   4)
    PH(3, 0, 2, ct0,     1, 128,   4)
    PH(0, 1, 0, ct0 + 1, 1, 128,   4)
    PH(1, 2, 1, ct0 + 1, 1, 65152, 4)
    PH(2, 0, 2, ct0 + 1, 1, 128,   4)
    PH(3, 1, 0, ct0 + 1, 1, 128,   4)
    PH(0, 2, 1, ct0 + 2, 1, 128,   4)
    PH(1, 0, 2, ct0 + 2, 1, 65152, 4)
    PH(2, 1, 0, ct0 + 2, 1, 128,   4)
    PH(3, 2, 1, ct0 + 2, 1, 128,   4)
  }
  // tail: ct = 63 (phases t=252..255; stages ts=254,255 then drain)
  {
    const int ctT = 63;
    PH(0, 0, 2, ctT, 1, 128, 4)
    PH(1, 1, 0, ctT, 1, 0,   4)
    PH(2, 2, 1, ctT, 0, 0,   0)
    PH(3, 0, 2, ctT, 0, 0,   0)
  }
#undef PH

  // per-row min across 16 l15-lanes; cross-wc merge via LDS (overlay on Bs)
  unsigned* dstar = (unsigned*)&Bs[0][0];   // [2][64]
  unsigned gmin[2][4];
  #pragma unroll
  for (int rf = 0; rf < 2; ++rf)
    #pragma unroll
    for (int rg = 0; rg < 4; ++rg) {
      unsigned g = b0k[rf][rg];
      #pragma unroll
      for (int m = 1; m < 16; m <<= 1)
        g = min(g, (unsigned)__shfl_xor((int)g, m, 64));
      gmin[rf][rg] = g;
      if (l15 == 0) dstar[wc * 64 + wr * 32 + rf * 16 + l4 * 4 + rg] = g;
    }
  __syncthreads();
  #pragma unroll
  for (int rf = 0; rf < 2; ++rf)
    #pragma unroll
    for (int rg = 0; rg < 4; ++rg) {
      int rl = wr * 32 + rf * 16 + l4 * 4 + rg;
      unsigned gg = min(gmin[rf][rg], dstar[(wc ^ 1) * 64 + rl]);
      float ds = __uint_as_float(gg & 0xFFFFFF00u);
      unsigned thr = __float_as_uint(ds + MARGIN);
      int base = (row0 + rl) * 96 + wc * 48 + l15 * 3;
      unsigned kk0 = b0k[rf][rg], kk1 = b1k[rf][rg], kk2 = b2k[rf][rg];
      int c0 = (int)((kk0 >> 2) & 63u) * 128 + wc * 64 + (int)(kk0 & 3u) * 16 + l15;
      int c1 = (int)((kk1 >> 2) & 63u) * 128 + wc * 64 + (int)(kk1 & 3u) * 16 + l15;
      int c2i = (int)((kk2 >> 2) & 63u) * 128 + wc * 64 + (int)(kk2 & 3u) * 16 + l15;
      cand[base + 0] = (kk0 <= thr) ? c0 : -1;
      cand[base + 1] = (kk1 <= thr) ? c1 : -1;
      cand[base + 2] = (kk2 <= thr) ? c2i : -1;
    }
}

// ---- exact fp64 refine over candidate set (one wave per row, 96 slots) -----
__global__ void vq_refine(const float* __restrict__ X, const float* __restrict__ Cb,
                          const int* __restrict__ cand, float* __restrict__ idx_out) {
  int row = (blockIdx.x * blockDim.x + threadIdx.x) >> 6;
  int lane = threadIdx.x & 63;
  if (row >= NTOK) return;
  int cv0 = cand[row * 96 + lane];
  int cv1 = (lane < 32) ? cand[row * 96 + 64 + lane] : -1;
  unsigned long long m0 = __ballot(cv0 >= 0);
  unsigned long long m1 = __ballot(cv1 >= 0);
  if (__popcll(m0) + __popcll(m1) == 1) {
    int idx;
    if (m0) idx = __shfl(cv0, __ffsll(m0) - 1, 64);
    else    idx = __shfl(cv1, __ffsll(m1) - 1, 64);
    if (lane == 0) idx_out[row] = (float)idx;
    return;
  }
  const float4* x4 = (const float4*)(X + (size_t)row * DIM);
  float4 xa = x4[lane * 2], xb = x4[lane * 2 + 1];
  double bestd = 1e300; int besti = 0x7FFFFFFF;
  #pragma unroll
  for (int part = 0; part < 2; ++part) {
    unsigned long long mm = part == 0 ? m0 : m1;
    int cv = part == 0 ? cv0 : cv1;
    while (mm) {
      int src = __ffsll(mm) - 1; mm &= mm - 1;
      int idx = __shfl(cv, src, 64);
      const float4* c4 = (const float4*)(Cb + (size_t)idx * DIM);
      float4 ca = c4[lane * 2], cb = c4[lane * 2 + 1];
      double dt = (double)xa.x*ca.x + (double)xa.y*ca.y + (double)xa.z*ca.z + (double)xa.w*ca.w
                + (double)xb.x*cb.x + (double)xb.y*cb.y + (double)xb.z*cb.z + (double)xb.w*cb.w;
      double cc = (double)ca.x*ca.x + (double)ca.y*ca.y + (double)ca.z*ca.z + (double)ca.w*ca.w
                + (double)cb.x*cb.x + (double)cb.y*cb.y + (double)cb.z*cb.z + (double)cb.w*cb.w;
      double sdist = cc - 2.0 * dt;           // x2 omitted: per-row constant
      #pragma unroll
      for (int off = 32; off; off >>= 1) sdist += __shfl_down(sdist, off, 64);
      if (lane == 0 && (sdist < bestd || (sdist == bestd && idx < besti))) { bestd = sdist; besti = idx; }
    }
  }
  if (lane == 0) idx_out[row] = (float)besti;
}

// ---- final: quantized = inputs (runs LAST; overwrites scratch) -------------
__global__ void vq_copy(const float* __restrict__ in, float* __restrict__ out, int n4) {
  int i = blockIdx.x * blockDim.x + threadIdx.x;
  int st = gridDim.x * blockDim.x;
  const float4* s = (const float4*)in;
  float4* d = (float4*)out;
  for (; i < n4; i += st) d[i] = s[i];
}

extern "C" void kernel_launch(void* const* d_in, const int* in_sizes, int n_in,
                              void* d_out, int out_size, void* d_ws, size_t ws_size,
                              hipStream_t stream) {
  const float* X  = (const float*)d_in[0];
  const float* Cb = (const float*)d_in[1];
  float* out = (float*)d_out;

  unsigned char* Xq   = (unsigned char*)out;                  // [N][512] fp8
  unsigned char* Cq   = (unsigned char*)(out + 4194304);      // [K][512] fp8
  int*           cand = (int*)(out + 5242880);                // [N][96]
  float*         c2   = (float*)d_ws;                         // [K]
  float*         idx_out = out + (size_t)NTOK * DIM;

  vq_prep8<<<KCODES / 4, 256, 0, stream>>>(Cb, Cq, c2, KCODES);
  vq_prep8<<<NTOK / 4, 256, 0, stream>>>(X, Xq, nullptr, NTOK);
  vq_main<<<NTOK / 64, 256, 0, stream>>>(Xq, Cq, c2, cand);
  vq_refine<<<NTOK / 4, 256, 0, stream>>>(X, Cb, cand, idx_out);
  vq_copy<<<2048, 256, 0, stream>>>(X, out, NTOK * DIM / 4);
}